// Round 8
// baseline (1178.946 us; speedup 1.0000x reference)
//
#include <hip/hip_runtime.h>
#include <hip/hip_bf16.h>

typedef __hip_bfloat16 bf16;
typedef short short8v __attribute__((ext_vector_type(8)));
typedef float float4v __attribute__((ext_vector_type(4)));

static __device__ __forceinline__ float b2f(bf16 x){ return __bfloat162float(x); }

// dtype-flexible input load: isbf ? bf16[i] : f32[i]
static __device__ __forceinline__ float ldin(const void* p, size_t i, bool isbf) {
  return isbf ? b2f(((const bf16*)p)[i]) : ((const float*)p)[i];
}

static __device__ __forceinline__ unsigned short f2bu(float f) {
  bf16 h = __float2bfloat16(f);
  return *reinterpret_cast<unsigned short*>(&h);
}

#define CDIV(a,b) (((a)+(b)-1)/(b))

// Model constants
#define NB   4
#define NSL  50
#define HWT  256
#define NT   306     // NSL + HWT
#define DIM  512
#define NH   8
#define FF   2048
#define RPP  28100   // mixed rel-pos pairs per batch
#define NPR  (NB*RPP) // 112400 total mixed pairs

// decode mixed-pair index q (0..RPP-1) -> (i,j)
static __device__ __forceinline__ void rp_decode(int q, int& i, int& j) {
  if (q < 15300) { i = q / NT; j = q % NT; }
  else { int r = q - 15300; i = NSL + r / NSL; j = r % NSL; }
}

// ---------------------------------------------------------------------------
// dtype detector (bf16 vs f32 served data); flag=1 means bf16.
// ---------------------------------------------------------------------------
__global__ void detect_k(const void* p, int* flag) {
  const unsigned short* u = (const unsigned short*)p;
  int t = threadIdx.x;
  int e = (u[t] >> 7) & 0xFF;
  __shared__ int anybad;
  if (t == 0) anybad = 0;
  __syncthreads();
  if (e >= 0x88) atomicOr(&anybad, 1);
  __syncthreads();
  if (t == 0) *flag = anybad ? 0 : 1;
}

// ---------------------------------------------------------------------------
// Batched weight transpose: all 17 weights in ONE launch.
// W[K,N] (bf16 or f32) -> WT[N,K] bf16; N mult of 64, K mult of 128.
// Tile 64n x 128k: write side emits 256B contiguous per n-row (4 thr x 64B).
// ---------------------------------------------------------------------------
struct WtArgs {
  const void* W[17];
  unsigned long long wto[17];
  int K[17], N[17];
  int base[18];
};

__global__ __launch_bounds__(256) void wtrans_all_k(WtArgs a, unsigned short* __restrict__ WT,
                                                    const int* __restrict__ flagp) {
  const bool isbf = *flagp != 0;
  int bid = blockIdx.x;
  int idx = 0;
#pragma unroll
  for (int i = 1; i < 17; ++i) if (bid >= a.base[i]) idx = i;
  int t0 = bid - a.base[idx];
  const int K = a.K[idx], N = a.N[idx];
  const int tilesN = N >> 6;
  const int perLayer = tilesN * (K >> 7);
  const int layer = t0 / perLayer, rem = t0 % perLayer;
  const int n0 = (rem % tilesN) * 64, k0 = (rem / tilesN) * 128;
  const void* W = a.W[idx];
  unsigned short* dst0 = WT + a.wto[idx];
  const size_t slice = (size_t)K * N * layer;

  __shared__ unsigned short S[64 * 136];
  int t = threadIdx.x;
  int kk = t >> 4, nn = (t & 15) * 4;
#pragma unroll
  for (int r = 0; r < 8; ++r) {
    int k = k0 + kk + r * 16;
    unsigned short v[4];
    if (isbf) {
      ushort4 u = *(const ushort4*)((const unsigned short*)W + slice + (size_t)k * N + n0 + nn);
      v[0]=u.x; v[1]=u.y; v[2]=u.z; v[3]=u.w;
    } else {
      float4 f = *(const float4*)((const float*)W + slice + (size_t)k * N + n0 + nn);
      v[0]=f2bu(f.x); v[1]=f2bu(f.y); v[2]=f2bu(f.z); v[3]=f2bu(f.w);
    }
#pragma unroll
    for (int i = 0; i < 4; ++i) S[(nn + i) * 136 + kk + r * 16] = v[i];
  }
  __syncthreads();
  int nr = t >> 2, kc = (t & 3) * 32;
  unsigned short* dst = dst0 + slice + (size_t)(n0 + nr) * K + k0 + kc;
#pragma unroll
  for (int i = 0; i < 4; ++i)
    *(short8v*)(dst + i * 8) = *(const short8v*)&S[nr * 136 + kc + i * 8];
}

// ---------------------------------------------------------------------------
// MFMA bf16 GEMM epilogue
// ---------------------------------------------------------------------------
static __device__ __forceinline__ void gemm_epi(
    float4v accv, int row0, int col,
    const void* __restrict__ bias, size_t boff,
    void* __restrict__ C, int oty,
    int M, int N, int kbeg,
    int act, int mode, int spec,
    const void* __restrict__ p0, const void* __restrict__ p1,
    bool isbf)
{
  float bv = (bias && kbeg == 0) ? ldin(bias, boff + col, isbf) : 0.f;
#pragma unroll
  for (int r = 0; r < 4; ++r) {
    int row = row0 + r;
    if (row >= M) continue;
    float v = accv[r] + bv;
    if (act == 1) v = fmaxf(v, 0.f);
    else if (act == 2) {
      float u = 0.7978845608028654f * (v + 0.044715f * v * v * v);
      v = 0.5f * v * (1.f + tanhf(u));
    } else if (act == 3) {
      v = v / (1.f + expf(-v));
    }
    if (spec == 2 && kbeg == 0) {
      int hh = (row >> 4) & 15, ww = row & 15;
      v += ldin(p0, hh * N + col, isbf) + ldin(p1, ww * N + col, isbf);
    }
    if (spec == 1) {
      int b_ = row / NT, n_ = row % NT;
      if (n_ >= NSL) {
        size_t oi = ((size_t)(b_ * HWT + (n_ - NSL))) * N + col;
        if (isbf) ((bf16*)C)[oi] = __float2bfloat16(v);
        else      ((float*)C)[oi] = v;
      }
    } else if (spec == 3) {
      size_t oi = (size_t)row * N + col;
      if (isbf) ((bf16*)C)[oi] = __float2bfloat16(v);
      else      ((float*)C)[oi] = v;
    } else {
      size_t idx = (size_t)row * N + col;
      if (oty) ((bf16*)C)[idx] = __float2bfloat16(v);
      else {
        float* Cf = (float*)C;
        if (mode == 2) atomicAdd(&Cf[idx], v);
        else if (mode == 1) Cf[idx] += v;
        else Cf[idx] = v;
      }
    }
  }
}

// ---------------------------------------------------------------------------
// MFMA bf16 GEMM body (64x64 tile): BK=64, WT[N,K] bf16, register prefetch.
// mode: 0=store, 1=accumulate, 2=atomicAdd (K-split). bias added iff kbeg==0.
// act: 0 none, 1 relu, 2 gelu(tanh), 3 silu. N%64==0, K%64==0.
// spec: 0 normal; 1 head-store (row%NT remap, skip slots);
//       2 patch pos-add epilogue (kbeg==0 only);
//       3 head A-remap (M=1024 token rows).
// ---------------------------------------------------------------------------
#define LDK 72
static __device__ __forceinline__ void gemm_body2(
    const void* __restrict__ A, int aty,
    const unsigned short* __restrict__ WT,
    const void* __restrict__ bias, size_t boff,
    void* __restrict__ C, int oty,
    int M, int N, int K, int kbeg, int kend,
    int act, int mode, int spec,
    const void* __restrict__ p0, const void* __restrict__ p1,
    bool isbf)
{
  __shared__ unsigned short As[64 * LDK];
  __shared__ unsigned short Bs[64 * LDK];
  const int tid = threadIdx.x;
  const int lane = tid & 63, wave = tid >> 6;
  const int quad = lane >> 4, ti = lane & 15;
  const int wm = (wave & 1) * 32, wn = (wave >> 1) * 32;
  const int bm = blockIdx.y * 64, bn = blockIdx.x * 64;
  const int srow = tid >> 2, sch = (tid & 3) * 16;

  unsigned short ha[16], hb[16];
  const int gm = bm + srow;
  const bool aok = gm < M;
  int arow = gm;
  if (spec == 3) arow = ((gm >> 8) * NT) + NSL + (gm & 255);
  const unsigned short* Abf = (const unsigned short*)A + (size_t)arow * K;
  const float*          Af  = (const float*)A + (size_t)arow * K;
  const unsigned short* Bp  = WT + (size_t)(bn + srow) * K;

  auto fetchA = [&](int k0) {
    if (aok) {
      if (aty) {
        const ushort4* ap = (const ushort4*)(Abf + k0 + sch);
#pragma unroll
        for (int i = 0; i < 4; ++i) {
          ushort4 u = ap[i];
          ha[i*4+0]=u.x; ha[i*4+1]=u.y; ha[i*4+2]=u.z; ha[i*4+3]=u.w;
        }
      } else {
        const float4* ap = (const float4*)(Af + k0 + sch);
#pragma unroll
        for (int i = 0; i < 4; ++i) {
          float4 f = ap[i];
          ha[i*4+0]=f2bu(f.x); ha[i*4+1]=f2bu(f.y); ha[i*4+2]=f2bu(f.z); ha[i*4+3]=f2bu(f.w);
        }
      }
    } else {
#pragma unroll
      for (int i = 0; i < 16; ++i) ha[i] = 0;
    }
  };
  auto fetchB = [&](int k0) {
    const ushort4* bp = (const ushort4*)(Bp + k0 + sch);
#pragma unroll
    for (int i = 0; i < 4; ++i) {
      ushort4 u = bp[i];
      hb[i*4+0]=u.x; hb[i*4+1]=u.y; hb[i*4+2]=u.z; hb[i*4+3]=u.w;
    }
  };

  float4v acc00 = {0,0,0,0}, acc01 = {0,0,0,0}, acc10 = {0,0,0,0}, acc11 = {0,0,0,0};
  fetchA(kbeg); fetchB(kbeg);
  for (int k0 = kbeg; k0 < kend; k0 += 64) {
    *(short8v*)&As[srow * LDK + sch]     = *(short8v*)ha;
    *(short8v*)&As[srow * LDK + sch + 8] = *(short8v*)(ha + 8);
    *(short8v*)&Bs[srow * LDK + sch]     = *(short8v*)hb;
    *(short8v*)&Bs[srow * LDK + sch + 8] = *(short8v*)(hb + 8);
    __syncthreads();
    if (k0 + 64 < kend) { fetchA(k0 + 64); fetchB(k0 + 64); }
#pragma unroll
    for (int ks = 0; ks < 2; ++ks) {
      short8v a0 = *reinterpret_cast<const short8v*>(&As[(wm + ti)      * LDK + ks * 32 + quad * 8]);
      short8v a1 = *reinterpret_cast<const short8v*>(&As[(wm + 16 + ti) * LDK + ks * 32 + quad * 8]);
      short8v b0 = *reinterpret_cast<const short8v*>(&Bs[(wn + ti)      * LDK + ks * 32 + quad * 8]);
      short8v b1 = *reinterpret_cast<const short8v*>(&Bs[(wn + 16 + ti) * LDK + ks * 32 + quad * 8]);
      acc00 = __builtin_amdgcn_mfma_f32_16x16x32_bf16(a0, b0, acc00, 0, 0, 0);
      acc01 = __builtin_amdgcn_mfma_f32_16x16x32_bf16(a0, b1, acc01, 0, 0, 0);
      acc10 = __builtin_amdgcn_mfma_f32_16x16x32_bf16(a1, b0, acc10, 0, 0, 0);
      acc11 = __builtin_amdgcn_mfma_f32_16x16x32_bf16(a1, b1, acc11, 0, 0, 0);
    }
    __syncthreads();
  }

  float4v accs[2][2] = {{acc00, acc01}, {acc10, acc11}};
#pragma unroll
  for (int mi = 0; mi < 2; ++mi)
#pragma unroll
    for (int ni = 0; ni < 2; ++ni)
      gemm_epi(accs[mi][ni], bm + wm + mi * 16 + quad * 4, bn + wn + ni * 16 + ti,
               bias, boff, C, oty, M, N, kbeg, act, mode, spec, p0, p1, isbf);
}

__global__ __launch_bounds__(256) void gemm_mfma(
    const void* A, int aty, const unsigned short* WT, size_t woff,
    const void* bias, size_t boff, void* C, int oty,
    int M, int N, int K, int act, int accum, int zsplit,
    int spec, const void* p0, const void* p1, const int* __restrict__ flagp)
{
  int ksz = K / zsplit;
  int kbeg = blockIdx.z * ksz;
  int mode = zsplit > 1 ? 2 : (accum ? 1 : 0);
  gemm_body2(A, aty, WT + woff, bias, boff, C, oty, M, N, K, kbeg, kbeg + ksz,
             act, mode, spec, p0, p1, *flagp != 0);
}

// 3 GEMMs sharing A/shapes (QKV); blockIdx.z selects job
__global__ __launch_bounds__(256) void gemm_mfma_tri(
    const void* A, int aty, const unsigned short* WT, size_t o0, size_t o1, size_t o2,
    void* C0, void* C1, void* C2, int oty, int M, int N, int K,
    const int* __restrict__ flagp)
{
  size_t o = blockIdx.z == 0 ? o0 : (blockIdx.z == 1 ? o1 : o2);
  void* C = blockIdx.z == 0 ? C0 : (blockIdx.z == 1 ? C1 : C2);
  gemm_body2(A, aty, WT + o, nullptr, 0, C, oty, M, N, K, 0, K, 0, 0, 0,
             nullptr, nullptr, *flagp != 0);
}

// 2 GEMMs, separate A/W/bias/C, shared shapes
__global__ __launch_bounds__(256) void gemm_mfma_duo(
    const void* A0, const void* A1, int aty, const unsigned short* WT, size_t o0, size_t o1,
    const void* bias0, const void* bias1, void* C0, void* C1, int oty,
    int M, int N, int K, const int* __restrict__ flagp)
{
  const void* A = blockIdx.z ? A1 : A0;
  size_t o = blockIdx.z ? o1 : o0;
  const void* bias = blockIdx.z ? bias1 : bias0;
  void* C = blockIdx.z ? C1 : C0;
  gemm_body2(A, aty, WT + o, bias, 0, C, oty, M, N, K, 0, K, 0, 0, 0,
             nullptr, nullptr, *flagp != 0);
}

// ---------------------------------------------------------------------------
// Fused rel-pos pipeline v3: synth silu(l1) vectorized -> MFMA l2 (two 64-col
// halves) -> silu -> MFMA l3 (W3^T bf16 padded to 16 rows) -> scatter to BIAS.
// One block = 64 pairs, LDS ~41KB. l3 serial fmaf chain replaced by 4 MFMA.
// ---------------------------------------------------------------------------
__global__ __launch_bounds__(256) void rp_fused_k(
    const float* __restrict__ CRD_, const void* w1, const void* b1,
    const unsigned short* __restrict__ WT, size_t woff,
    const void* b2, const void* w3, const void* b3,
    float* __restrict__ bias, const int* __restrict__ flagp)
{
  const bool isbf = *flagp != 0;
  __shared__ unsigned short As[64 * 136];   // h1; later h2 cols 0..63
  __shared__ unsigned short Bs[64 * 136];   // W2T half; later h2 cols 64..127
  __shared__ unsigned short W3B[16 * 136];  // W3^T bf16, rows 8..15 zero
  __shared__ float W1s[384];                // w1 (256) + b1 (128)
  const int tid = threadIdx.x;
  const int lane = tid & 63, wave = tid >> 6, quad = lane >> 4, ti = lane & 15;
  const int wm = (wave & 1) * 32, wn = (wave >> 1) * 32;
  const int bm = blockIdx.x * 64;

  // stage W1/b1 and W3^T (bf16, padded)
  for (int e = tid; e < 384; e += 256)
    W1s[e] = (e < 256) ? ldin(w1, e, isbf) : ldin(b1, e - 256, isbf);
  for (int e = tid; e < 2048; e += 256) {
    int hh = e >> 7, k = e & 127;
    W3B[hh * 136 + k] = (hh < 8) ? f2bu(ldin(w3, (size_t)k * 8 + hh, isbf)) : (unsigned short)0;
  }
  __syncthreads();

  // synth h1 = silu(rel @ w1 + b1) -> As (vectorized, reg-buffered)
  {
    int r = tid >> 2, k0 = (tid & 3) * 32;
    int p = bm + r;
    float r0 = 0.f, r1 = 0.f;
    bool ok = p < NPR;
    if (ok) {
      int q = p % RPP, bb = p / RPP;
      int ii, jj; rp_decode(q, ii, jj);
      r0 = CRD_[(bb * NT + ii) * 2]     - CRD_[(bb * NT + jj) * 2];
      r1 = CRD_[(bb * NT + ii) * 2 + 1] - CRD_[(bb * NT + jj) * 2 + 1];
    }
    unsigned short hbuf[32];
#pragma unroll 8
    for (int k = 0; k < 32; ++k) {
      int kk = k0 + k;
      float a = fmaf(r0, W1s[kk], fmaf(r1, W1s[128 + kk], W1s[256 + kk]));
      a = a / (1.f + __expf(-a));
      hbuf[k] = ok ? f2bu(a) : (unsigned short)0;
    }
#pragma unroll
    for (int i = 0; i < 4; ++i)
      *(short8v*)&As[r * 136 + k0 + i * 8] = *(short8v*)&hbuf[i * 8];
  }

  float4v acc[2][2][2];   // [half][mi][ni]
#pragma unroll
  for (int hf = 0; hf < 2; ++hf)
#pragma unroll
    for (int mi = 0; mi < 2; ++mi)
#pragma unroll
      for (int ni = 0; ni < 2; ++ni) acc[hf][mi][ni] = (float4v){0,0,0,0};

#pragma unroll
  for (int hf = 0; hf < 2; ++hf) {
    // stage Bs = W2T rows [hf*64, hf*64+64), K=128
    {
      int nrow = tid >> 2, kc = (tid & 3) * 32;
      const unsigned short* src = WT + woff + (size_t)(hf * 64 + nrow) * 128 + kc;
      // half 0: barrier below also covers As writes; half 1: waits Bs reads done
      __syncthreads();
#pragma unroll
      for (int i = 0; i < 4; ++i)
        *(short8v*)&Bs[nrow * 136 + kc + i * 8] = *(const short8v*)(src + i * 8);
    }
    __syncthreads();
#pragma unroll
    for (int ks = 0; ks < 4; ++ks) {
      short8v a0 = *(const short8v*)&As[(wm + ti)      * 136 + ks * 32 + quad * 8];
      short8v a1 = *(const short8v*)&As[(wm + 16 + ti) * 136 + ks * 32 + quad * 8];
      short8v b0 = *(const short8v*)&Bs[(wn + ti)      * 136 + ks * 32 + quad * 8];
      short8v b1 = *(const short8v*)&Bs[(wn + 16 + ti) * 136 + ks * 32 + quad * 8];
      acc[hf][0][0] = __builtin_amdgcn_mfma_f32_16x16x32_bf16(a0, b0, acc[hf][0][0], 0, 0, 0);
      acc[hf][0][1] = __builtin_amdgcn_mfma_f32_16x16x32_bf16(a0, b1, acc[hf][0][1], 0, 0, 0);
      acc[hf][1][0] = __builtin_amdgcn_mfma_f32_16x16x32_bf16(a1, b0, acc[hf][1][0], 0, 0, 0);
      acc[hf][1][1] = __builtin_amdgcn_mfma_f32_16x16x32_bf16(a1, b1, acc[hf][1][1], 0, 0, 0);
    }
  }
  __syncthreads();   // all MFMA reads of As/Bs complete

  // h2 = silu(acc + b2) -> bf16 into As (cols 0..63) / Bs (cols 64..127)
#pragma unroll
  for (int hf = 0; hf < 2; ++hf)
#pragma unroll
    for (int mi = 0; mi < 2; ++mi)
#pragma unroll
      for (int ni = 0; ni < 2; ++ni) {
        int row0 = wm + mi * 16 + quad * 4;
        int col  = hf * 64 + wn + ni * 16 + ti;
        float bv = ldin(b2, col, isbf);
        unsigned short* dst = hf ? Bs : As;
        int c = col & 63;
#pragma unroll
        for (int r = 0; r < 4; ++r) {
          float v = acc[hf][mi][ni][r] + bv;
          v = v / (1.f + __expf(-v));
          dst[(row0 + r) * 136 + c] = f2bu(v);
        }
      }
  __syncthreads();

  // l3 via MFMA: out[64 pairs][8 heads] = h2[64][128] @ W3[128][8].
  // Wave w handles pair rows w*16..w*16+15; cols = 16 (8 valid heads).
  {
    float4v acc3 = {0,0,0,0};
#pragma unroll
    for (int ks = 0; ks < 2; ++ks) {
      short8v a = *(const short8v*)&As[(wave * 16 + ti) * 136 + ks * 32 + quad * 8];
      short8v b = *(const short8v*)&W3B[ti * 136 + ks * 32 + quad * 8];
      acc3 = __builtin_amdgcn_mfma_f32_16x16x32_bf16(a, b, acc3, 0, 0, 0);
    }
#pragma unroll
    for (int ks = 0; ks < 2; ++ks) {
      short8v a = *(const short8v*)&Bs[(wave * 16 + ti) * 136 + ks * 32 + quad * 8];
      short8v b = *(const short8v*)&W3B[ti * 136 + (ks + 2) * 32 + quad * 8];
      acc3 = __builtin_amdgcn_mfma_f32_16x16x32_bf16(a, b, acc3, 0, 0, 0);
    }
    // C layout: col(head)=ti, row(pair-in-tile)=quad*4+r
    if (ti < 8) {
      float bv3 = ldin(b3, ti, isbf);
      int p0r = bm + wave * 16 + quad * 4;
#pragma unroll
      for (int r = 0; r < 4; ++r) {
        int pp = p0r + r;
        if (pp < NPR) {
          int q = pp % RPP, bb = pp / RPP;
          int ii, jj; rp_decode(q, ii, jj);
          bias[((size_t)(bb * NH + ti) * NT + ii) * NT + jj] = acc3[r] + bv3;
        }
      }
    }
  }
}

// ---------------------------------------------------------------------------
// merged: slot coords (s2c) + token grid coords + rel-pos 31x31 delta table.
// grid 1162: 0..199 slot rows; 200 token coords; 201..1161 table entries.
// ---------------------------------------------------------------------------
__global__ __launch_bounds__(256) void coords_table_k(
    const float* __restrict__ slots, const void* __restrict__ w,
    const void* __restrict__ bv,
    const void* w1, const void* b1, const void* w2, const void* b2,
    const void* w3, const void* b3,
    float* __restrict__ coords, float* __restrict__ tab,
    const int* __restrict__ flagp) {
  const bool isbf = *flagp != 0;
  __shared__ float r0[256], r1[256];
  __shared__ float h1[128], h2[128];
  int blk = blockIdx.x, t = threadIdx.x;
  if (blk < 200) {
    int b = blk / 50, n = blk % 50;
    const float* x = slots + (size_t)blk * DIM;
    float v0 = x[t], v1 = x[t + 256];
    float a0 = v0 * ldin(w, 2 * t, isbf)     + v1 * ldin(w, 2 * (t + 256), isbf);
    float a1 = v0 * ldin(w, 2 * t + 1, isbf) + v1 * ldin(w, 2 * (t + 256) + 1, isbf);
    r0[t] = a0; r1[t] = a1;
    __syncthreads();
    for (int o = 128; o > 0; o >>= 1) {
      if (t < o) { r0[t] += r0[t + o]; r1[t] += r1[t + o]; }
      __syncthreads();
    }
    if (t == 0) {
      coords[((size_t)b * NT + n) * 2]     = r0[0] + ldin(bv, 0, isbf);
      coords[((size_t)b * NT + n) * 2 + 1] = r1[0] + ldin(bv, 1, isbf);
    }
  } else if (blk == 200) {
#pragma unroll
    for (int s = 0; s < 4; ++s) {
      int i = t + 256 * s;
      int b = i >> 8, tt = i & 255;
      coords[((size_t)b * NT + NSL + tt) * 2]     = (float)(tt >> 4);
      coords[((size_t)b * NT + NSL + tt) * 2 + 1] = (float)(tt & 15);
    }
  } else {
    int e = blk - 201;   // 0..960
    float rr0 = (float)(e / 31 - 15), rr1 = (float)(e % 31 - 15);
    if (t < 128) {
      float a = fmaf(rr0, ldin(w1, t, isbf), fmaf(rr1, ldin(w1, 128 + t, isbf), ldin(b1, t, isbf)));
      h1[t] = a / (1.f + expf(-a));
    }
    __syncthreads();
    if (t < 128) {
      float s = ldin(b2, t, isbf);
#pragma unroll 4
      for (int k = 0; k < 128; ++k) s = fmaf(h1[k], ldin(w2, k * 128 + t, isbf), s);
      h2[t] = s / (1.f + expf(-s));
    }
    __syncthreads();
    if (t < 8) {
      float o = ldin(b3, t, isbf);
#pragma unroll 4
      for (int k = 0; k < 128; ++k) o = fmaf(h2[k], ldin(w3, k * 8 + t, isbf), o);
      tab[e * 8 + t] = o;
    }
  }
}

// ---------------------------------------------------------------------------
// merged: patch extraction (im2col) -> bf16  +  slots init.
// grid 3472: 0..3071 patchify; 3072..3471 slots.
// ---------------------------------------------------------------------------
__global__ void prep_k(const void* __restrict__ img, unsigned short* __restrict__ xp,
                       const void* __restrict__ mu, const void* __restrict__ ls,
                       const void* __restrict__ noise, float* __restrict__ slots,
                       const int* __restrict__ flagp) {
  const bool isbf = *flagp != 0;
  int blk = blockIdx.x;
  if (blk < 3072) {
    int i = blk * 256 + threadIdx.x;     // exact: 3072*256 = NB*HWT*768
    int col = i % 768, row = i / 768;
    int c = col % 3, p2 = (col / 3) & 15, p1 = col / 48;
    int w = row & 15, h = (row >> 4) & 15, b = row >> 8;
    xp[i] = f2bu(ldin(img, (((size_t)(b * 3 + c) * 256 + h * 16 + p1) * 256) + w * 16 + p2, isbf));
  } else {
    int i = (blk - 3072) * 256 + threadIdx.x;  // exact: 400*256 = NB*NSL*DIM
    int d = i & 511;
    slots[i] = ldin(mu, d, isbf) + expf(ldin(ls, d, isbf)) * ldin(noise, i, isbf);
  }
}

// ---------------------------------------------------------------------------
// LayerNorm (bf16 out) / RMSNorm (bf16 out) over 512-dim rows
// ---------------------------------------------------------------------------
__global__ void ln512_k(const float* __restrict__ X, const void* __restrict__ g,
                        const void* __restrict__ b, unsigned short* __restrict__ Y,
                        const int* __restrict__ flagp) {
  const bool isbf = *flagp != 0;
  int row = blockIdx.x, t = threadIdx.x;
  const float* x = X + (size_t)row * DIM;
  float v0 = x[t], v1 = x[t + 256];
  __shared__ float rs[256], rq[256];
  rs[t] = v0 + v1; rq[t] = v0 * v0 + v1 * v1;
  __syncthreads();
  for (int o = 128; o > 0; o >>= 1) {
    if (t < o) { rs[t] += rs[t + o]; rq[t] += rq[t + o]; }
    __syncthreads();
  }
  float mean = rs[0] * (1.f / 512.f);
  float var  = rq[0] * (1.f / 512.f) - mean * mean;
  float inv  = rsqrtf(var + 1e-5f);
  unsigned short* y = Y + (size_t)row * DIM;
  y[t]       = f2bu((v0 - mean) * inv * ldin(g, t, isbf)       + ldin(b, t, isbf));
  y[t + 256] = f2bu((v1 - mean) * inv * ldin(g, t + 256, isbf) + ldin(b, t + 256, isbf));
}

__global__ void rms512_k(const float* __restrict__ X, const void* __restrict__ g,
                         int goff, unsigned short* __restrict__ Y, const int* __restrict__ flagp) {
  const bool isbf = *flagp != 0;
  int row = blockIdx.x, t = threadIdx.x;
  const float* x = X + (size_t)row * DIM;
  float v0 = x[t], v1 = x[t + 256];
  __shared__ float rq[256];
  rq[t] = v0 * v0 + v1 * v1;
  __syncthreads();
  for (int o = 128; o > 0; o >>= 1) {
    if (t < o) rq[t] += rq[t + o];
    __syncthreads();
  }
  float nrm = sqrtf(rq[0]);
  float sc = 22.62741699796952f / fmaxf(nrm, 1e-12f);
  unsigned short* y = Y + (size_t)row * DIM;
  y[t]       = f2bu(v0 * sc * ldin(g, goff + t, isbf));
  y[t + 256] = f2bu(v1 * sc * ldin(g, goff + t + 256, isbf));
}

// ---------------------------------------------------------------------------
// Slot attention pieces (split kernels — high occupancy)
// ---------------------------------------------------------------------------
__global__ void slot_dots_k(const float* __restrict__ q, const float* __restrict__ k,
                            float* __restrict__ dots) {
  int blk = blockIdx.x;                 // b*200 + h*50 + i
  int i = blk % 50, h = (blk / 50) & 3, b = blk / 200;
  int j = threadIdx.x;
  __shared__ float qs[64];
  if (threadIdx.x < 64) qs[threadIdx.x] = q[((size_t)(b * 50 + i)) * 256 + h * 64 + threadIdx.x];
  __syncthreads();
  const float* kr = k + ((size_t)(b * 256 + j)) * 256 + h * 64;
  float s = 0.f;
#pragma unroll 8
  for (int d = 0; d < 64; ++d) s = fmaf(qs[d], kr[d], s);
  dots[(((size_t)(b * 4 + h) * 50) + i) * 256 + j] = s * 0.125f;
}

// column-wise softmax over slots + 1e-8 (renorm folded into slot_upd_k)
__global__ void colsm_k(float* __restrict__ dots) {
  int idx = blockIdx.x * 256 + threadIdx.x;
  if (idx >= 4096) return;
  int j = idx & 255, bh = idx >> 8;
  float* base = dots + ((size_t)bh * NSL) * 256 + j;
  float v[NSL];
#pragma unroll
  for (int i = 0; i < NSL; ++i) v[i] = base[i * 256];
  float m = -1e30f;
#pragma unroll
  for (int i = 0; i < NSL; ++i) m = fmaxf(m, v[i]);
  float s = 0.f;
#pragma unroll
  for (int i = 0; i < NSL; ++i) { float e = __expf(v[i] - m); v[i] = e; s += e; }
  float inv = 1.f / s;
#pragma unroll
  for (int i = 0; i < NSL; ++i) base[i * 256] = fmaf(v[i], inv, 1e-8f);
}

// upd[i][d] = sum_j a[i][j] v[j][d] / sum_j a[i][j]  (renorm folded)
__global__ void slot_upd_k(const float* __restrict__ attn, const float* __restrict__ v,
                           float* __restrict__ upd) {
  int bi = blockIdx.x;        // b*50+i
  int b = bi / 50, i = bi % 50;
  int t = threadIdx.x, h = t >> 6, lane = t & 63;
  const float* arow = attn + ((size_t)((b * 4 + h) * 50) + i) * 256;
  // wave-level row sum (h uniform within wave)
  float s4 = arow[lane] + arow[lane + 64] + arow[lane + 128] + arow[lane + 192];
#pragma unroll
  for (int o = 1; o < 64; o <<= 1) s4 += __shfl_xor(s4, o);
  float inv = 1.f / s4;
  float s = 0.f;
  for (int j = 0; j < 256; ++j) s = fmaf(arow[j], v[((size_t)(b * 256 + j)) * 256 + t], s);
  upd[(size_t)bi * 256 + t] = s * inv;
}

// fused GRU + LayerNorm(ff): one row per block; writes SLOTS f32 + SLNB bf16
__global__ __launch_bounds__(256) void gruln_k(
    const float* __restrict__ gx, const float* __restrict__ gh,
    float* __restrict__ slots, const void* __restrict__ g, const void* __restrict__ bb,
    unsigned short* __restrict__ Y, const int* __restrict__ flagp) {
  const bool isbf = *flagp != 0;
  int row = blockIdx.x, t = threadIdx.x;
  size_t b3 = (size_t)row * 1536;
  float s01[2];
#pragma unroll
  for (int half = 0; half < 2; ++half) {
    int d = t + half * 256;
    float xr = gx[b3 + d], xz = gx[b3 + 512 + d], xn = gx[b3 + 1024 + d];
    float hr = gh[b3 + d], hz = gh[b3 + 512 + d], hn = gh[b3 + 1024 + d];
    float r = 1.f / (1.f + expf(-(xr + hr)));
    float z = 1.f / (1.f + expf(-(xz + hz)));
    float n = tanhf(xn + r * hn);
    float prev = slots[(size_t)row * DIM + d];
    s01[half] = (1.f - z) * n + z * prev;
    slots[(size_t)row * DIM + d] = s01[half];
  }
  __shared__ float rs[256], rq[256];
  rs[t] = s01[0] + s01[1];
  rq[t] = s01[0] * s01[0] + s01[1] * s01[1];
  __syncthreads();
  for (int o = 128; o > 0; o >>= 1) {
    if (t < o) { rs[t] += rs[t + o]; rq[t] += rq[t + o]; }
    __syncthreads();
  }
  float mean = rs[0] * (1.f / 512.f);
  float var  = rq[0] * (1.f / 512.f) - mean * mean;
  float inv  = rsqrtf(var + 1e-5f);
  unsigned short* y = Y + (size_t)row * DIM;
  y[t]       = f2bu((s01[0] - mean) * inv * ldin(g, t, isbf)       + ldin(bb, t, isbf));
  y[t + 256] = f2bu((s01[1] - mean) * inv * ldin(g, t + 256, isbf) + ldin(bb, t + 256, isbf));
}

// ---------------------------------------------------------------------------
// Transformer pieces
// ---------------------------------------------------------------------------
__global__ void build_x_k(const float* __restrict__ slots, const float* __restrict__ tok,
                          float* __restrict__ x) {
  int i = blockIdx.x * 256 + threadIdx.x;
  if (i >= NB * NT * DIM) return;
  int d = i & 511, n = (i >> 9) % NT, b = i / (NT * DIM);
  x[i] = (n < NSL) ? slots[((size_t)(b * NSL + n)) * DIM + d]
                   : tok[((size_t)(b * HWT + (n - NSL))) * DIM + d];
}

// ---------------------------------------------------------------------------
// Fused attention: per block = 32 q-rows x one (b,h). S = QK^T*0.125 + bias
// (f32 LDS), in-block softmax (8 lanes/row), P bf16 in place, O = P V.
// Token-token bias from 31x31 delta TABLE staged in LDS; slot pairs read BIAS.
// grid (10, 32). LDS ~60 KB.
// ---------------------------------------------------------------------------
__global__ __launch_bounds__(256) void attn_fused_k(
    const unsigned short* __restrict__ Qb, const unsigned short* __restrict__ Kb,
    const unsigned short* __restrict__ Vb, const float* __restrict__ bias,
    const float* __restrict__ tab, unsigned short* __restrict__ Ob)
{
  const int bh = blockIdx.y, b = bh >> 3, h = bh & 7;
  const int i0 = blockIdx.x * 32;
  __shared__ unsigned short Qs[32 * 72];
  __shared__ unsigned short Ks[64 * 72];
  __shared__ float S[32 * 332];
  __shared__ float TabS[961];
  unsigned short* P = (unsigned short*)S;   // bf16 prob, row stride 664 shorts

  const int tid = threadIdx.x;
  const int lane = tid & 63, wave = tid >> 6, quad = lane >> 4, ti = lane & 15;
  const int mi = wave & 1, nh = wave >> 1;

  // ---- stage token-token delta table (h slice) ----
  for (int e = tid; e < 961; e += 256) TabS[e] = tab[e * 8 + h];

  // ---- load Q tile (32 x 64) ----
  {
    int r = tid >> 3, c = (tid & 7) * 8;
    int gi = i0 + r;
    ushort4 u0 = {0,0,0,0}, u1 = {0,0,0,0};
    if (gi < NT) {
      const ushort4* p = (const ushort4*)(Qb + ((size_t)(b * NT + gi)) * DIM + h * 64 + c);
      u0 = p[0]; u1 = p[1];
    }
    *(ushort4*)&Qs[r * 72 + c] = u0;
    *(ushort4*)&Qs[r * 72 + c + 4] = u1;
  }

  // ---- phase 1: scores ----
  for (int kt = 0; kt < 5; ++kt) {
    __syncthreads();
    {
      int kr = tid >> 2, c = (tid & 3) * 16;
      int gj = kt * 64 + kr;
      ushort4 v[4] = {{0,0,0,0},{0,0,0,0},{0,0,0,0},{0,0,0,0}};
      if (gj < NT) {
        const ushort4* p = (const ushort4*)(Kb + ((size_t)(b * NT + gj)) * DIM + h * 64 + c);
#pragma unroll
        for (int i = 0; i < 4; ++i) v[i] = p[i];
      }
#pragma unroll
      for (int i = 0; i < 4; ++i) *(ushort4*)&Ks[kr * 72 + c + i * 4] = v[i];
    }
    __syncthreads();
#pragma unroll
    for (int ntl = 0; ntl < 2; ++ntl) {
      int nt = nh * 2 + ntl;
      float4v acc = {0,0,0,0};
#pragma unroll
      for (int ks = 0; ks < 2; ++ks) {
        short8v a  = *(const short8v*)&Qs[(mi * 16 + ti) * 72 + ks * 32 + quad * 8];
        short8v bb = *(const short8v*)&Ks[(nt * 16 + ti) * 72 + ks * 32 + quad * 8];
        acc = __builtin_amdgcn_mfma_f32_16x16x32_bf16(a, bb, acc, 0, 0, 0);
      }
      int colL = kt * 64 + nt * 16 + ti;
      int row0 = mi * 16 + quad * 4;
#pragma unroll
      for (int r = 0; r < 4; ++r) {
        int row_g = i0 + row0 + r;
        float val;
        if (colL < NT) {
          float bv = 0.f;
          if (row_g < NT) {
            if (row_g >= NSL && colL >= NSL) {
              int ii = row_g - NSL, jj = colL - NSL;
              int di = (ii >> 4) - (jj >> 4) + 15;
              int dj = (ii & 15) - (jj & 15) + 15;
              bv = TabS[di * 31 + dj];
            } else {
              bv = bias[((size_t)bh * NT + row_g) * NT + colL];
            }
          }
          val = acc[r] * 0.125f + bv;
        } else val = -1e30f;
        S[(row0 + r) * 332 + colL] = val;
      }
    }
  }
  __syncthreads();

  // ---- phase 2: softmax (rows in regs), write P bf16 in place ----
  {
    int rl = tid >> 3, sub = tid & 7;
    float sv[40];
#pragma unroll
    for (int k = 0; k < 40; ++k) sv[k] = S[rl * 332 + sub + k * 8];
    float m = -1e30f;
#pragma unroll
    for (int k = 0; k < 40; ++k) m = fmaxf(m, sv[k]);
    m = fmaxf(m, __shfl_xor(m, 1));
    m = fmaxf(m, __shfl_xor(m, 2));
    m = fmaxf(m, __shfl_xor(m, 4));
    float s = 0.f;
#pragma unroll
    for (int k = 0; k < 40; ++k) { float e = __expf(sv[k] - m); sv[k] = e; s += e; }
    s += __shfl_xor(s, 1);
    s += __shfl_xor(s, 2);
    s += __shfl_xor(s, 4);
    float inv = 1.f / s;
    __syncthreads();   // all S reads complete before bf16 overwrite
#pragma unroll
    for (int k = 0; k < 40; ++k) P[rl * 664 + sub + k * 8] = f2bu(sv[k] * inv);
  }

  // ---- phase 3: O = P V ----
  float4v oacc[2] = {{0,0,0,0},{0,0,0,0}};
  for (int vt = 0; vt < 5; ++vt) {
    __syncthreads();
    {
      int key = tid & 63, d0 = (tid >> 6) * 16;
      int gj = vt * 64 + key;
      unsigned short hv[16];
      if (gj < NT) {
        const ushort4* p = (const ushort4*)(Vb + ((size_t)(b * NT + gj)) * DIM + h * 64 + d0);
#pragma unroll
        for (int i = 0; i < 4; ++i) {
          ushort4 u = p[i];
          hv[i*4+0]=u.x; hv[i*4+1]=u.y; hv[i*4+2]=u.z; hv[i*4+3]=u.w;
        }
      } else {
#pragma unroll
        for (int i = 0; i < 16; ++i) hv[i] = 0;
      }
#pragma unroll
      for (int i = 0; i < 16; ++i) Ks[(d0 + i) * 72 + key] = hv[i];
    }
    __syncthreads();
#pragma unroll
    for (int ntl = 0; ntl < 2; ++ntl) {
      int nt = nh * 2 + ntl;
#pragma unroll
      for (int ks = 0; ks < 2; ++ks) {
        short8v a  = *(const short8v*)&P[(mi * 16 + ti) * 664 + vt * 64 + ks * 32 + quad * 8];
        short8v bb = *(const short8v*)&Ks[(nt * 16 + ti) * 72 + ks * 32 + quad * 8];
        oacc[ntl] = __builtin_amdgcn_mfma_f32_16x16x32_bf16(a, bb, oacc[ntl], 0, 0, 0);
      }
    }
  }

  // ---- write O ----
#pragma unroll
  for (int ntl = 0; ntl < 2; ++ntl) {
    int dim = nh * 32 + ntl * 16 + ti;
#pragma unroll
    for (int r = 0; r < 4; ++r) {
      int row_g = i0 + mi * 16 + quad * 4 + r;
      if (row_g < NT)
        Ob[((size_t)(b * NT + row_g)) * DIM + h * 64 + dim] = f2bu(oacc[ntl][r]);
    }
  }
}

// ---------------------------------------------------------------------------
extern "C" void kernel_launch(void* const* d_in, const int* in_sizes, int n_in,
                              void* d_out, int out_size, void* d_ws, size_t ws_size,
                              hipStream_t stream) {
  const void* images        = d_in[0];
  const void* slot_noise    = d_in[1];
  const void* patch_w       = d_in[2];
  const void* patch_b       = d_in[3];
  const void* hpos          = d_in[4];
  const void* wpos          = d_in[5];
  const void* rp_w1         = d_in[6];
  const void* rp_b1         = d_in[7];
  const void* rp_w2         = d_in[8];
  const void* rp_b2         = d_in[9];
  const void* rp_w3         = d_in[10];
  const void* rp_b3         = d_in[11];
  const void* slots_mu      = d_in[12];
  const void* slots_logsig  = d_in[13];
  const void* sa_ln_in_g    = d_in[14];
  const void* sa_ln_in_b    = d_in[15];
  const void* sa_ln_sl_g    = d_in[16];
  const void* sa_ln_sl_b    = d_in[17];
  const void* sa_wq         = d_in[18];
  const void* sa_bq         = d_in[19];
  const void* sa_wk         = d_in[20];
  const void* sa_bk         = d_in[21];
  const void* sa_wv         = d_in[22];
  const void* sa_bv         = d_in[23];
  const void* sa_wo         = d_in[24];
  const void* sa_bo         = d_in[25];
  const void* gru_wih       = d_in[26];
  const void* gru_whh       = d_in[27];
  const void* gru_bih       = d_in[28];
  const void* gru_bhh       = d_in[29];
  const void* sa_ln_ff_g    = d_in[30];
  const void* sa_ln_ff_b    = d_in[31];
  const void* sa_mlp_w1     = d_in[32];
  const void* sa_mlp_b1     = d_in[33];
  const void* sa_mlp_w2     = d_in[34];
  const void* sa_mlp_b2     = d_in[35];
  const void* s2c_w         = d_in[36];
  const void* s2c_b         = d_in[37];
  const void* attn_g        = d_in[38];
  const void* wq            = d_in[39];
  const void* wk            = d_in[40];
  const void* wv            = d_in[41];
  const void* wo            = d_in[42];
  const void* ff_g          = d_in[43];
  const void* ff_w1         = d_in[44];
  const void* ff_b1         = d_in[45];
  const void* ff_w2         = d_in[46];
  const void* ff_b2         = d_in[47];
  const void* final_g       = d_in[48];
  const void* pred_w        = d_in[49];
  const void* pred_b        = d_in[50];

  float* ws = (float*)d_ws;
  int* FLAG = (int*)ws;
  size_t off = 16;
  auto alloc = [&](size_t n) { float* p = ws + off; off += (n + 15) & ~(size_t)15; return p; };
  float* TOK   = alloc((size_t)NB * HWT * DIM);
  unsigned short* INPB = (unsigned short*)alloc((size_t)NB * HWT * DIM / 2);
  float* KB    = alloc((size_t)NB * HWT * 256);
  float* VB    = alloc((size_t)NB * HWT * 256);
  float* SLOTS = alloc((size_t)NB * NSL * DIM);
  unsigned short* SLNB = (unsigned short*)alloc((size_t)NB * NSL * DIM / 2);
  float* QB    = alloc((size_t)NB * NSL * 256);
  float* ATT   = alloc((size_t)NB * 4 * NSL * HWT);
  float* UPD   = alloc((size_t)NB * NSL * 256);
  float* UPDP  = alloc((size_t)NB * NSL * DIM);
  unsigned short* HIDSB = (unsigned short*)alloc((size_t)NB * NSL * DIM / 2);
  float* CRD   = alloc((size_t)NB * NT * 2);
  float* TAB   = alloc((size_t)961 * 8);
  float* BIAS  = alloc((size_t)NB * NH * NT * NT);
  float* X     = alloc((size_t)NB * NT * DIM);
  unsigned short* HBB  = (unsigned short*)alloc((size_t)NB * NT * DIM / 2);
  unsigned short* QHB  = (unsigned short*)alloc((size_t)NB * NT * DIM / 2);
  unsigned short* KHB  = (unsigned short*)alloc((size_t)NB * NT * DIM / 2);
  unsigned short* VHB  = (unsigned short*)alloc((size_t)NB * NT * DIM / 2);
  float* SIM   = alloc((size_t)NB * NH * NT * NT);        // GRU-gate alias space
  unsigned short* OBB  = (unsigned short*)alloc((size_t)NB * NT * DIM / 2);
  unsigned short* FFHB = (unsigned short*)alloc((size_t)NB * NT * FF / 2);
  float* OUTT  = alloc((size_t)NB * NT * DIM);
  // aliases (dead-region reuse)
  unsigned short* XPB = (unsigned short*)OUTT;            // im2col; OUTT otherwise unused
  float* GX = SIM;                                        // GRU gates; dead before transformer
  float* GH = SIM + (size_t)NB * NSL * 1536;
  // transposed-weight arena (bf16 [N,K] per weight)
  const size_t oPatch = 0;
  const size_t oKw    = oPatch + (size_t)512 * 768;
  const size_t oVw    = oKw    + (size_t)256 * 512;
  const size_t oQw    = oVw    + (size_t)256 * 512;
  const size_t oWo    = oQw    + (size_t)256 * 512;
  const size_t oGih   = oWo    + (size_t)512 * 256;
  const size_t oGhh   = oGih   + (size_t)1536 * 512;
  const size_t oMlp1  = oGhh   + (size_t)1536 * 512;
  const size_t oMlp2  = oMlp1  + (size_t)512 * 512;
  const size_t oRp2   = oMlp2  + (size_t)512 * 512;
  const size_t oWq    = oRp2   + (size_t)128 * 128;
  const size_t oWk    = oWq    + (size_t)6 * 512 * 512;
  const size_t oWv    = oWk    + (size_t)6 * 512 * 512;
  const size_t oWol   = oWv    + (size_t)6 * 512 * 512;
  const size_t oFf1   = oWol   + (size_t)6 * 512 * 512;
  const size_t oFf2   = oFf1   + (size_t)6 * 512 * 2048;
  const size_t oPred  = oFf2   + (size_t)6 * 2048 * 512;
  const size_t wtTotal = oPred + (size_t)512 * 512;
  unsigned short* WTS = (unsigned short*)alloc((wtTotal + 1) / 2);
  (void)ws_size; (void)in_sizes; (void)n_in; (void)out_size;

#define GEMMM(A_, ATY_, WOFF_, BIAS_, BOFF_, C_, OTY_, M_, N_, K_, ACT_, ACC_, ZS_, SPEC_, P0_, P1_) \
  gemm_mfma<<<dim3((N_)/64, CDIV((M_),64), (ZS_)), 256, 0, stream>>>( \
      A_, ATY_, WTS, (size_t)(WOFF_), BIAS_, (size_t)(BOFF_), C_, OTY_, M_, N_, K_, ACT_, ACC_, ZS_, \
      SPEC_, P0_, P1_, FLAG)

  const int MROW = NB * NT;   // 1224
  const int MS   = NB * NSL;  // 200

  // ---- dtype detection; merged patchify+slots_init; batched weight transpose ----
  detect_k<<<1, 256, 0, stream>>>(images, FLAG);
  prep_k<<<3472, 256, 0, stream>>>(images, XPB, slots_mu, slots_logsig, slot_noise, SLOTS, FLAG);
  {
    WtArgs a;
    const void* Wp[17] = { patch_w, sa_wk, sa_wv, sa_wq, sa_wo, gru_wih, gru_whh,
                           sa_mlp_w1, sa_mlp_w2, rp_w2, wq, wk, wv, wo, ff_w1, ff_w2, pred_w };
    const size_t Oo[17] = { oPatch, oKw, oVw, oQw, oWo, oGih, oGhh,
                            oMlp1, oMlp2, oRp2, oWq, oWk, oWv, oWol, oFf1, oFf2, oPred };
    const int Kk[17] = {768,512,512,512,256,512,512,512,512,128,512,512,512,512,512,2048,512};
    const int Nn[17] = {512,256,256,256,512,1536,1536,512,512,128,512,512,512,512,2048,512,512};
    const int Ll[17] = {1,1,1,1,1,1,1,1,1,1,6,6,6,6,6,6,1};
    int acc = 0;
    for (int i = 0; i < 17; ++i) {
      a.W[i] = Wp[i]; a.wto[i] = Oo[i]; a.K[i] = Kk[i]; a.N[i] = Nn[i];
      a.base[i] = acc;
      acc += Ll[i] * (Kk[i] >> 7) * (Nn[i] >> 6);
    }
    a.base[17] = acc;
    wtrans_all_k<<<acc, 256, 0, stream>>>(a, WTS, FLAG);
  }

  // ---- patch embed (K-split 3, atomic into zeroed TOK; bias+pos at kbeg==0) ----
  hipMemsetAsync(TOK, 0, (size_t)NB * HWT * DIM * sizeof(float), stream);
  GEMMM(XPB, 1, oPatch, patch_b, 0, TOK, 0, NB*HWT, DIM, 768, 0, 0, 3, 2, hpos, wpos);

  // ---- slot attention: k, v ----
  ln512_k<<<NB*HWT, 256, 0, stream>>>(TOK, sa_ln_in_g, sa_ln_in_b, INPB, FLAG);
  gemm_mfma_duo<<<dim3(4, 16, 2), 256, 0, stream>>>(
      INPB, INPB, 1, WTS, oKw, oVw, sa_bk, sa_bv, KB, VB, 0, NB*HWT, 256, DIM, FLAG);

  for (int it = 0; it < 3; ++it) {
    ln512_k<<<MS, 256, 0, stream>>>(SLOTS, sa_ln_sl_g, sa_ln_sl_b, SLNB, FLAG);
    GEMMM(SLNB, 1, oQw, sa_bq, 0, QB, 0, MS, 256, DIM, 0, 0, 1, 0, nullptr, nullptr);
    slot_dots_k<<<NB*4*NSL, 256, 0, stream>>>(QB, KB, ATT);
    colsm_k<<<16, 256, 0, stream>>>(ATT);
    slot_upd_k<<<MS, 256, 0, stream>>>(ATT, VB, UPD);
    GEMMM(UPD, 0, oWo, sa_bo, 0, UPDP, 0, MS, DIM, 256, 0, 0, 1, 0, nullptr, nullptr);
    gemm_mfma_duo<<<dim3(24, 4, 2), 256, 0, stream>>>(
        UPDP, SLOTS, 0, WTS, oGih, oGhh, gru_bih, gru_bhh, GX, GH, 0, MS, 1536, DIM, FLAG);
    gruln_k<<<MS, 256, 0, stream>>>(GX, GH, SLOTS, sa_ln_ff_g, sa_ln_ff_b, SLNB, FLAG);
    GEMMM(SLNB, 1, oMlp1, sa_mlp_b1, 0, HIDSB, 1, MS, DIM, DIM, 1, 0, 1, 0, nullptr, nullptr);
    GEMMM(HIDSB, 1, oMlp2, sa_mlp_b2, 0, SLOTS, 0, MS, DIM, DIM, 0, 1, 1, 0, nullptr, nullptr);
  }

  // ---- rel-pos bias (fused MLP for slot-involving pairs; token-token via TAB) ----
  coords_table_k<<<1162, 256, 0, stream>>>(SLOTS, s2c_w, s2c_b,
      rp_w1, rp_b1, rp_w2, rp_b2, rp_w3, rp_b3, CRD, TAB, FLAG);
  rp_fused_k<<<CDIV(NPR, 64), 256, 0, stream>>>(
      CRD, rp_w1, rp_b1, WTS, oRp2, rp_b2, rp_w3, rp_b3, BIAS, FLAG);

  // ---- transformer ----
  build_x_k<<<CDIV(NB*NT*DIM, 256), 256, 0, stream>>>(SLOTS, TOK, X);
  for (int l = 0; l < 6; ++l) {
    size_t lw = (size_t)l * 512 * 512;
    rms512_k<<<MROW, 256, 0, stream>>>(X, attn_g, l * DIM, HBB, FLAG);
    gemm_mfma_tri<<<dim3(8, 20, 3), 256, 0, stream>>>(
        HBB, 1, WTS, oWq + lw, oWk + lw, oWv + lw, QHB, KHB, VHB, 1, MROW, DIM, DIM, FLAG);
    attn_fused_k<<<dim3(10, NB*NH), 256, 0, stream>>>(QHB, KHB, VHB, BIAS, TAB, OBB);
    GEMMM(OBB, 1, oWol + lw, (const void*)nullptr, 0, X, 0, MROW, DIM, DIM, 0, 1, 2, 0, nullptr, nullptr);
    rms512_k<<<MROW, 256, 0, stream>>>(X, ff_g, l * DIM, HBB, FLAG);
    GEMMM(HBB, 1, oFf1 + (size_t)l * 512 * 2048, ff_b1, l * FF, FFHB, 1, MROW, FF, DIM, 2, 0, 1, 0, nullptr, nullptr);
    GEMMM(FFHB, 1, oFf2 + (size_t)l * 2048 * 512, ff_b2, l * DIM, X, 0, MROW, DIM, FF, 0, 1, 4, 0, nullptr, nullptr);
  }

  // ---- head: final RMSNorm + GEMM over token rows only (A-remap, M=1024) ----
  rms512_k<<<MROW, 256, 0, stream>>>(X, final_g, 0, HBB, FLAG);
  GEMMM(HBB, 1, oPred, pred_b, 0, d_out, 0, 1024, DIM, DIM, 0, 0, 1, 3, nullptr, nullptr);

#undef GEMMM
}

// Round 9
// 1147.344 us; speedup vs baseline: 1.0275x; 1.0275x over previous
//
#include <hip/hip_runtime.h>
#include <hip/hip_bf16.h>

typedef __hip_bfloat16 bf16;
typedef short short8v __attribute__((ext_vector_type(8)));
typedef float float4v __attribute__((ext_vector_type(4)));

static __device__ __forceinline__ float b2f(bf16 x){ return __bfloat162float(x); }

// dtype-flexible input load: isbf ? bf16[i] : f32[i]
static __device__ __forceinline__ float ldin(const void* p, size_t i, bool isbf) {
  return isbf ? b2f(((const bf16*)p)[i]) : ((const float*)p)[i];
}

static __device__ __forceinline__ unsigned short f2bu(float f) {
  bf16 h = __float2bfloat16(f);
  return *reinterpret_cast<unsigned short*>(&h);
}

#define CDIV(a,b) (((a)+(b)-1)/(b))

// Model constants
#define NB   4
#define NSL  50
#define HWT  256
#define NT   306     // NSL + HWT
#define DIM  512
#define NH   8
#define FF   2048
#define RPP  28100   // mixed rel-pos pairs per batch
#define NPR  (NB*RPP) // 112400 total mixed pairs

// decode mixed-pair index q (0..RPP-1) -> (i,j)
static __device__ __forceinline__ void rp_decode(int q, int& i, int& j) {
  if (q < 15300) { i = q / NT; j = q % NT; }
  else { int r = q - 15300; i = NSL + r / NSL; j = r % NSL; }
}

// ---------------------------------------------------------------------------
// dtype detector (bf16 vs f32 served data); flag=1 means bf16.
// ---------------------------------------------------------------------------
__global__ void detect_k(const void* p, int* flag) {
  const unsigned short* u = (const unsigned short*)p;
  int t = threadIdx.x;
  int e = (u[t] >> 7) & 0xFF;
  __shared__ int anybad;
  if (t == 0) anybad = 0;
  __syncthreads();
  if (e >= 0x88) atomicOr(&anybad, 1);
  __syncthreads();
  if (t == 0) *flag = anybad ? 0 : 1;
}

// ---------------------------------------------------------------------------
// Batched weight transpose: all 17 weights in ONE launch.
// W[K,N] (bf16 or f32) -> WT[N,K] bf16; N mult of 64, K mult of 128.
// Tile 64n x 128k: write side emits 256B contiguous per n-row (4 thr x 64B).
// ---------------------------------------------------------------------------
struct WtArgs {
  const void* W[17];
  unsigned long long wto[17];
  int K[17], N[17];
  int base[18];
};

__global__ __launch_bounds__(256) void wtrans_all_k(WtArgs a, unsigned short* __restrict__ WT,
                                                    const int* __restrict__ flagp) {
  const bool isbf = *flagp != 0;
  int bid = blockIdx.x;
  int idx = 0;
#pragma unroll
  for (int i = 1; i < 17; ++i) if (bid >= a.base[i]) idx = i;
  int t0 = bid - a.base[idx];
  const int K = a.K[idx], N = a.N[idx];
  const int tilesN = N >> 6;
  const int perLayer = tilesN * (K >> 7);
  const int layer = t0 / perLayer, rem = t0 % perLayer;
  const int n0 = (rem % tilesN) * 64, k0 = (rem / tilesN) * 128;
  const void* W = a.W[idx];
  unsigned short* dst0 = WT + a.wto[idx];
  const size_t slice = (size_t)K * N * layer;

  __shared__ unsigned short S[64 * 136];
  int t = threadIdx.x;
  int kk = t >> 4, nn = (t & 15) * 4;
#pragma unroll
  for (int r = 0; r < 8; ++r) {
    int k = k0 + kk + r * 16;
    unsigned short v[4];
    if (isbf) {
      ushort4 u = *(const ushort4*)((const unsigned short*)W + slice + (size_t)k * N + n0 + nn);
      v[0]=u.x; v[1]=u.y; v[2]=u.z; v[3]=u.w;
    } else {
      float4 f = *(const float4*)((const float*)W + slice + (size_t)k * N + n0 + nn);
      v[0]=f2bu(f.x); v[1]=f2bu(f.y); v[2]=f2bu(f.z); v[3]=f2bu(f.w);
    }
#pragma unroll
    for (int i = 0; i < 4; ++i) S[(nn + i) * 136 + kk + r * 16] = v[i];
  }
  __syncthreads();
  int nr = t >> 2, kc = (t & 3) * 32;
  unsigned short* dst = dst0 + slice + (size_t)(n0 + nr) * K + k0 + kc;
#pragma unroll
  for (int i = 0; i < 4; ++i)
    *(short8v*)(dst + i * 8) = *(const short8v*)&S[nr * 136 + kc + i * 8];
}

// ---------------------------------------------------------------------------
// MFMA bf16 GEMM epilogue
// ---------------------------------------------------------------------------
static __device__ __forceinline__ void gemm_epi(
    float4v accv, int row0, int col,
    const void* __restrict__ bias, size_t boff,
    void* __restrict__ C, int oty,
    int M, int N, int kbeg,
    int act, int mode, int spec,
    const void* __restrict__ p0, const void* __restrict__ p1,
    bool isbf)
{
  float bv = (bias && kbeg == 0) ? ldin(bias, boff + col, isbf) : 0.f;
#pragma unroll
  for (int r = 0; r < 4; ++r) {
    int row = row0 + r;
    if (row >= M) continue;
    float v = accv[r] + bv;
    if (act == 1) v = fmaxf(v, 0.f);
    else if (act == 2) {
      float u = 0.7978845608028654f * (v + 0.044715f * v * v * v);
      v = 0.5f * v * (1.f + tanhf(u));
    } else if (act == 3) {
      v = v / (1.f + expf(-v));
    }
    if (spec == 2 && kbeg == 0) {
      int hh = (row >> 4) & 15, ww = row & 15;
      v += ldin(p0, hh * N + col, isbf) + ldin(p1, ww * N + col, isbf);
    }
    if (spec == 1) {
      int b_ = row / NT, n_ = row % NT;
      if (n_ >= NSL) {
        size_t oi = ((size_t)(b_ * HWT + (n_ - NSL))) * N + col;
        if (isbf) ((bf16*)C)[oi] = __float2bfloat16(v);
        else      ((float*)C)[oi] = v;
      }
    } else if (spec == 3) {
      size_t oi = (size_t)row * N + col;
      if (isbf) ((bf16*)C)[oi] = __float2bfloat16(v);
      else      ((float*)C)[oi] = v;
    } else {
      size_t idx = (size_t)row * N + col;
      if (oty) ((bf16*)C)[idx] = __float2bfloat16(v);
      else {
        float* Cf = (float*)C;
        if (mode == 2) atomicAdd(&Cf[idx], v);
        else if (mode == 1) Cf[idx] += v;
        else Cf[idx] = v;
      }
    }
  }
}

// ---------------------------------------------------------------------------
// MFMA bf16 GEMM body (64x64 tile): BK=64, WT[N,K] bf16, register prefetch.
// mode: 0=store, 1=accumulate, 2=atomicAdd (K-split). bias added iff kbeg==0.
// act: 0 none, 1 relu, 2 gelu(tanh), 3 silu. N%64==0, K%64==0.
// spec: 0 normal; 1 head-store (row%NT remap, skip slots);
//       2 patch pos-add epilogue (kbeg==0 only);
//       3 head A-remap (M=1024 token rows).
// ---------------------------------------------------------------------------
#define LDK 72
static __device__ __forceinline__ void gemm_body2(
    const void* __restrict__ A, int aty,
    const unsigned short* __restrict__ WT,
    const void* __restrict__ bias, size_t boff,
    void* __restrict__ C, int oty,
    int M, int N, int K, int kbeg, int kend,
    int act, int mode, int spec,
    const void* __restrict__ p0, const void* __restrict__ p1,
    bool isbf)
{
  __shared__ unsigned short As[64 * LDK];
  __shared__ unsigned short Bs[64 * LDK];
  const int tid = threadIdx.x;
  const int lane = tid & 63, wave = tid >> 6;
  const int quad = lane >> 4, ti = lane & 15;
  const int wm = (wave & 1) * 32, wn = (wave >> 1) * 32;
  const int bm = blockIdx.y * 64, bn = blockIdx.x * 64;
  const int srow = tid >> 2, sch = (tid & 3) * 16;

  unsigned short ha[16], hb[16];
  const int gm = bm + srow;
  const bool aok = gm < M;
  int arow = gm;
  if (spec == 3) arow = ((gm >> 8) * NT) + NSL + (gm & 255);
  const unsigned short* Abf = (const unsigned short*)A + (size_t)arow * K;
  const float*          Af  = (const float*)A + (size_t)arow * K;
  const unsigned short* Bp  = WT + (size_t)(bn + srow) * K;

  auto fetchA = [&](int k0) {
    if (aok) {
      if (aty) {
        const ushort4* ap = (const ushort4*)(Abf + k0 + sch);
#pragma unroll
        for (int i = 0; i < 4; ++i) {
          ushort4 u = ap[i];
          ha[i*4+0]=u.x; ha[i*4+1]=u.y; ha[i*4+2]=u.z; ha[i*4+3]=u.w;
        }
      } else {
        const float4* ap = (const float4*)(Af + k0 + sch);
#pragma unroll
        for (int i = 0; i < 4; ++i) {
          float4 f = ap[i];
          ha[i*4+0]=f2bu(f.x); ha[i*4+1]=f2bu(f.y); ha[i*4+2]=f2bu(f.z); ha[i*4+3]=f2bu(f.w);
        }
      }
    } else {
#pragma unroll
      for (int i = 0; i < 16; ++i) ha[i] = 0;
    }
  };
  auto fetchB = [&](int k0) {
    const ushort4* bp = (const ushort4*)(Bp + k0 + sch);
#pragma unroll
    for (int i = 0; i < 4; ++i) {
      ushort4 u = bp[i];
      hb[i*4+0]=u.x; hb[i*4+1]=u.y; hb[i*4+2]=u.z; hb[i*4+3]=u.w;
    }
  };

  float4v acc00 = {0,0,0,0}, acc01 = {0,0,0,0}, acc10 = {0,0,0,0}, acc11 = {0,0,0,0};
  fetchA(kbeg); fetchB(kbeg);
  for (int k0 = kbeg; k0 < kend; k0 += 64) {
    *(short8v*)&As[srow * LDK + sch]     = *(short8v*)ha;
    *(short8v*)&As[srow * LDK + sch + 8] = *(short8v*)(ha + 8);
    *(short8v*)&Bs[srow * LDK + sch]     = *(short8v*)hb;
    *(short8v*)&Bs[srow * LDK + sch + 8] = *(short8v*)(hb + 8);
    __syncthreads();
    if (k0 + 64 < kend) { fetchA(k0 + 64); fetchB(k0 + 64); }
#pragma unroll
    for (int ks = 0; ks < 2; ++ks) {
      short8v a0 = *reinterpret_cast<const short8v*>(&As[(wm + ti)      * LDK + ks * 32 + quad * 8]);
      short8v a1 = *reinterpret_cast<const short8v*>(&As[(wm + 16 + ti) * LDK + ks * 32 + quad * 8]);
      short8v b0 = *reinterpret_cast<const short8v*>(&Bs[(wn + ti)      * LDK + ks * 32 + quad * 8]);
      short8v b1 = *reinterpret_cast<const short8v*>(&Bs[(wn + 16 + ti) * LDK + ks * 32 + quad * 8]);
      acc00 = __builtin_amdgcn_mfma_f32_16x16x32_bf16(a0, b0, acc00, 0, 0, 0);
      acc01 = __builtin_amdgcn_mfma_f32_16x16x32_bf16(a0, b1, acc01, 0, 0, 0);
      acc10 = __builtin_amdgcn_mfma_f32_16x16x32_bf16(a1, b0, acc10, 0, 0, 0);
      acc11 = __builtin_amdgcn_mfma_f32_16x16x32_bf16(a1, b1, acc11, 0, 0, 0);
    }
    __syncthreads();
  }

  float4v accs[2][2] = {{acc00, acc01}, {acc10, acc11}};
#pragma unroll
  for (int mi = 0; mi < 2; ++mi)
#pragma unroll
    for (int ni = 0; ni < 2; ++ni)
      gemm_epi(accs[mi][ni], bm + wm + mi * 16 + quad * 4, bn + wn + ni * 16 + ti,
               bias, boff, C, oty, M, N, kbeg, act, mode, spec, p0, p1, isbf);
}

__global__ __launch_bounds__(256) void gemm_mfma(
    const void* A, int aty, const unsigned short* WT, size_t woff,
    const void* bias, size_t boff, void* C, int oty,
    int M, int N, int K, int act, int accum, int zsplit,
    int spec, const void* p0, const void* p1, const int* __restrict__ flagp)
{
  int ksz = K / zsplit;
  int kbeg = blockIdx.z * ksz;
  int mode = zsplit > 1 ? 2 : (accum ? 1 : 0);
  gemm_body2(A, aty, WT + woff, bias, boff, C, oty, M, N, K, kbeg, kbeg + ksz,
             act, mode, spec, p0, p1, *flagp != 0);
}

// 3 GEMMs sharing A/shapes (QKV); blockIdx.z selects job
__global__ __launch_bounds__(256) void gemm_mfma_tri(
    const void* A, int aty, const unsigned short* WT, size_t o0, size_t o1, size_t o2,
    void* C0, void* C1, void* C2, int oty, int M, int N, int K,
    const int* __restrict__ flagp)
{
  size_t o = blockIdx.z == 0 ? o0 : (blockIdx.z == 1 ? o1 : o2);
  void* C = blockIdx.z == 0 ? C0 : (blockIdx.z == 1 ? C1 : C2);
  gemm_body2(A, aty, WT + o, nullptr, 0, C, oty, M, N, K, 0, K, 0, 0, 0,
             nullptr, nullptr, *flagp != 0);
}

// 2 GEMMs, separate A/W/bias/C, shared shapes
__global__ __launch_bounds__(256) void gemm_mfma_duo(
    const void* A0, const void* A1, int aty, const unsigned short* WT, size_t o0, size_t o1,
    const void* bias0, const void* bias1, void* C0, void* C1, int oty,
    int M, int N, int K, const int* __restrict__ flagp)
{
  const void* A = blockIdx.z ? A1 : A0;
  size_t o = blockIdx.z ? o1 : o0;
  const void* bias = blockIdx.z ? bias1 : bias0;
  void* C = blockIdx.z ? C1 : C0;
  gemm_body2(A, aty, WT + o, bias, 0, C, oty, M, N, K, 0, K, 0, 0, 0,
             nullptr, nullptr, *flagp != 0);
}

// ---------------------------------------------------------------------------
// Fused rel-pos pipeline v4: = v2 (round-7 structure: scalar f32 l3 with
// W3^T [8][132] in LDS) + __expf silu (round-8's verified cheap exp).
// One block = 64 pairs, LDS ~41KB.
// ---------------------------------------------------------------------------
__global__ __launch_bounds__(256) void rp_fused_k(
    const float* __restrict__ CRD_, const void* w1, const void* b1,
    const unsigned short* __restrict__ WT, size_t woff,
    const void* b2, const void* w3, const void* b3,
    float* __restrict__ bias, const int* __restrict__ flagp)
{
  const bool isbf = *flagp != 0;
  __shared__ unsigned short As[64 * 136];   // h1; later h2 cols 0..63
  __shared__ unsigned short Bs[64 * 136];   // W2T half; later h2 cols 64..127
  __shared__ float W3s[8 * 132];            // W3 transposed [head][k]
  __shared__ float W1s[384];                // w1 (256) + b1 (128)
  const int tid = threadIdx.x;
  const int lane = tid & 63, wave = tid >> 6, quad = lane >> 4, ti = lane & 15;
  const int wm = (wave & 1) * 32, wn = (wave >> 1) * 32;
  const int bm = blockIdx.x * 64;

  // stage W1/b1 and W3^T
  for (int e = tid; e < 384; e += 256)
    W1s[e] = (e < 256) ? ldin(w1, e, isbf) : ldin(b1, e - 256, isbf);
  for (int e = tid; e < 1024; e += 256) {
    int k = e >> 3, hh = e & 7;
    W3s[hh * 132 + k] = ldin(w3, e, isbf);
  }
  __syncthreads();

  // synth h1 = silu(rel @ w1 + b1) -> As (vectorized, reg-buffered)
  {
    int r = tid >> 2, k0 = (tid & 3) * 32;
    int p = bm + r;
    float r0 = 0.f, r1 = 0.f;
    bool ok = p < NPR;
    if (ok) {
      int q = p % RPP, bb = p / RPP;
      int ii, jj; rp_decode(q, ii, jj);
      r0 = CRD_[(bb * NT + ii) * 2]     - CRD_[(bb * NT + jj) * 2];
      r1 = CRD_[(bb * NT + ii) * 2 + 1] - CRD_[(bb * NT + jj) * 2 + 1];
    }
    unsigned short hbuf[32];
#pragma unroll 8
    for (int k = 0; k < 32; ++k) {
      int kk = k0 + k;
      float a = fmaf(r0, W1s[kk], fmaf(r1, W1s[128 + kk], W1s[256 + kk]));
      a = a / (1.f + __expf(-a));
      hbuf[k] = ok ? f2bu(a) : (unsigned short)0;
    }
#pragma unroll
    for (int i = 0; i < 4; ++i)
      *(short8v*)&As[r * 136 + k0 + i * 8] = *(short8v*)&hbuf[i * 8];
  }

  float4v acc[2][2][2];   // [half][mi][ni]
#pragma unroll
  for (int hf = 0; hf < 2; ++hf)
#pragma unroll
    for (int mi = 0; mi < 2; ++mi)
#pragma unroll
      for (int ni = 0; ni < 2; ++ni) acc[hf][mi][ni] = (float4v){0,0,0,0};

#pragma unroll
  for (int hf = 0; hf < 2; ++hf) {
    // stage Bs = W2T rows [hf*64, hf*64+64), K=128
    {
      int nrow = tid >> 2, kc = (tid & 3) * 32;
      const unsigned short* src = WT + woff + (size_t)(hf * 64 + nrow) * 128 + kc;
      // half 0: barrier below also covers As writes; half 1: waits Bs reads done
      __syncthreads();
#pragma unroll
      for (int i = 0; i < 4; ++i)
        *(short8v*)&Bs[nrow * 136 + kc + i * 8] = *(const short8v*)(src + i * 8);
    }
    __syncthreads();
#pragma unroll
    for (int ks = 0; ks < 4; ++ks) {
      short8v a0 = *(const short8v*)&As[(wm + ti)      * 136 + ks * 32 + quad * 8];
      short8v a1 = *(const short8v*)&As[(wm + 16 + ti) * 136 + ks * 32 + quad * 8];
      short8v b0 = *(const short8v*)&Bs[(wn + ti)      * 136 + ks * 32 + quad * 8];
      short8v b1 = *(const short8v*)&Bs[(wn + 16 + ti) * 136 + ks * 32 + quad * 8];
      acc[hf][0][0] = __builtin_amdgcn_mfma_f32_16x16x32_bf16(a0, b0, acc[hf][0][0], 0, 0, 0);
      acc[hf][0][1] = __builtin_amdgcn_mfma_f32_16x16x32_bf16(a0, b1, acc[hf][0][1], 0, 0, 0);
      acc[hf][1][0] = __builtin_amdgcn_mfma_f32_16x16x32_bf16(a1, b0, acc[hf][1][0], 0, 0, 0);
      acc[hf][1][1] = __builtin_amdgcn_mfma_f32_16x16x32_bf16(a1, b1, acc[hf][1][1], 0, 0, 0);
    }
  }
  __syncthreads();   // all MFMA reads of As/Bs complete

  // h2 = silu(acc + b2) -> bf16 into As (cols 0..63) / Bs (cols 64..127)
#pragma unroll
  for (int hf = 0; hf < 2; ++hf)
#pragma unroll
    for (int mi = 0; mi < 2; ++mi)
#pragma unroll
      for (int ni = 0; ni < 2; ++ni) {
        int row0 = wm + mi * 16 + quad * 4;
        int col  = hf * 64 + wn + ni * 16 + ti;
        float bv = ldin(b2, col, isbf);
        unsigned short* dst = hf ? Bs : As;
        int c = col & 63;
#pragma unroll
        for (int r = 0; r < 4; ++r) {
          float v = acc[hf][mi][ni][r] + bv;
          v = v / (1.f + __expf(-v));
          dst[(row0 + r) * 136 + c] = f2bu(v);
        }
      }
  __syncthreads();

  // l3: out[pair][head] = h2 . W3[:,head] + b3[head]; 2 passes x 32 pairs
#pragma unroll
  for (int s = 0; s < 2; ++s) {
    int item = tid + s * 256;
    int r = item >> 3, hh = item & 7;
    int p = bm + r;
    if (p < NPR) {
      int q = p % RPP, bb = p / RPP;
      int ii, jj; rp_decode(q, ii, jj);
      float sacc = ldin(b3, hh, isbf);
      const float* wrow = &W3s[hh * 132];
#pragma unroll 8
      for (int k4 = 0; k4 < 16; ++k4) {
        ushort4 h4 = *(const ushort4*)&As[r * 136 + k4 * 4];
        float4  w4 = *(const float4*)(wrow + k4 * 4);
        sacc = fmaf(b2f(*reinterpret_cast<bf16*>(&h4.x)), w4.x, sacc);
        sacc = fmaf(b2f(*reinterpret_cast<bf16*>(&h4.y)), w4.y, sacc);
        sacc = fmaf(b2f(*reinterpret_cast<bf16*>(&h4.z)), w4.z, sacc);
        sacc = fmaf(b2f(*reinterpret_cast<bf16*>(&h4.w)), w4.w, sacc);
      }
#pragma unroll 8
      for (int k4 = 0; k4 < 16; ++k4) {
        ushort4 h4 = *(const ushort4*)&Bs[r * 136 + k4 * 4];
        float4  w4 = *(const float4*)(wrow + 64 + k4 * 4);
        sacc = fmaf(b2f(*reinterpret_cast<bf16*>(&h4.x)), w4.x, sacc);
        sacc = fmaf(b2f(*reinterpret_cast<bf16*>(&h4.y)), w4.y, sacc);
        sacc = fmaf(b2f(*reinterpret_cast<bf16*>(&h4.z)), w4.z, sacc);
        sacc = fmaf(b2f(*reinterpret_cast<bf16*>(&h4.w)), w4.w, sacc);
      }
      bias[((size_t)(bb * NH + hh) * NT + ii) * NT + jj] = sacc;
    }
  }
}

// ---------------------------------------------------------------------------
// merged: slot coords (s2c) + token grid coords + rel-pos 31x31 delta table.
// grid 1162: 0..199 slot rows; 200 token coords; 201..1161 table entries.
// ---------------------------------------------------------------------------
__global__ __launch_bounds__(256) void coords_table_k(
    const float* __restrict__ slots, const void* __restrict__ w,
    const void* __restrict__ bv,
    const void* w1, const void* b1, const void* w2, const void* b2,
    const void* w3, const void* b3,
    float* __restrict__ coords, float* __restrict__ tab,
    const int* __restrict__ flagp) {
  const bool isbf = *flagp != 0;
  __shared__ float r0[256], r1[256];
  __shared__ float h1[128], h2[128];
  int blk = blockIdx.x, t = threadIdx.x;
  if (blk < 200) {
    int b = blk / 50, n = blk % 50;
    const float* x = slots + (size_t)blk * DIM;
    float v0 = x[t], v1 = x[t + 256];
    float a0 = v0 * ldin(w, 2 * t, isbf)     + v1 * ldin(w, 2 * (t + 256), isbf);
    float a1 = v0 * ldin(w, 2 * t + 1, isbf) + v1 * ldin(w, 2 * (t + 256) + 1, isbf);
    r0[t] = a0; r1[t] = a1;
    __syncthreads();
    for (int o = 128; o > 0; o >>= 1) {
      if (t < o) { r0[t] += r0[t + o]; r1[t] += r1[t + o]; }
      __syncthreads();
    }
    if (t == 0) {
      coords[((size_t)b * NT + n) * 2]     = r0[0] + ldin(bv, 0, isbf);
      coords[((size_t)b * NT + n) * 2 + 1] = r1[0] + ldin(bv, 1, isbf);
    }
  } else if (blk == 200) {
#pragma unroll
    for (int s = 0; s < 4; ++s) {
      int i = t + 256 * s;
      int b = i >> 8, tt = i & 255;
      coords[((size_t)b * NT + NSL + tt) * 2]     = (float)(tt >> 4);
      coords[((size_t)b * NT + NSL + tt) * 2 + 1] = (float)(tt & 15);
    }
  } else {
    int e = blk - 201;   // 0..960
    float rr0 = (float)(e / 31 - 15), rr1 = (float)(e % 31 - 15);
    if (t < 128) {
      float a = fmaf(rr0, ldin(w1, t, isbf), fmaf(rr1, ldin(w1, 128 + t, isbf), ldin(b1, t, isbf)));
      h1[t] = a / (1.f + expf(-a));
    }
    __syncthreads();
    if (t < 128) {
      float s = ldin(b2, t, isbf);
#pragma unroll 4
      for (int k = 0; k < 128; ++k) s = fmaf(h1[k], ldin(w2, k * 128 + t, isbf), s);
      h2[t] = s / (1.f + expf(-s));
    }
    __syncthreads();
    if (t < 8) {
      float o = ldin(b3, t, isbf);
#pragma unroll 4
      for (int k = 0; k < 128; ++k) o = fmaf(h2[k], ldin(w3, k * 8 + t, isbf), o);
      tab[e * 8 + t] = o;
    }
  }
}

// ---------------------------------------------------------------------------
// merged: patch extraction (im2col) -> bf16  +  slots init.
// grid 3472: 0..3071 patchify; 3072..3471 slots.
// ---------------------------------------------------------------------------
__global__ void prep_k(const void* __restrict__ img, unsigned short* __restrict__ xp,
                       const void* __restrict__ mu, const void* __restrict__ ls,
                       const void* __restrict__ noise, float* __restrict__ slots,
                       const int* __restrict__ flagp) {
  const bool isbf = *flagp != 0;
  int blk = blockIdx.x;
  if (blk < 3072) {
    int i = blk * 256 + threadIdx.x;     // exact: 3072*256 = NB*HWT*768
    int col = i % 768, row = i / 768;
    int c = col % 3, p2 = (col / 3) & 15, p1 = col / 48;
    int w = row & 15, h = (row >> 4) & 15, b = row >> 8;
    xp[i] = f2bu(ldin(img, (((size_t)(b * 3 + c) * 256 + h * 16 + p1) * 256) + w * 16 + p2, isbf));
  } else {
    int i = (blk - 3072) * 256 + threadIdx.x;  // exact: 400*256 = NB*NSL*DIM
    int d = i & 511;
    slots[i] = ldin(mu, d, isbf) + expf(ldin(ls, d, isbf)) * ldin(noise, i, isbf);
  }
}

// ---------------------------------------------------------------------------
// LayerNorm (bf16 out) / RMSNorm (bf16 out) over 512-dim rows
// ---------------------------------------------------------------------------
__global__ void ln512_k(const float* __restrict__ X, const void* __restrict__ g,
                        const void* __restrict__ b, unsigned short* __restrict__ Y,
                        const int* __restrict__ flagp) {
  const bool isbf = *flagp != 0;
  int row = blockIdx.x, t = threadIdx.x;
  const float* x = X + (size_t)row * DIM;
  float v0 = x[t], v1 = x[t + 256];
  __shared__ float rs[256], rq[256];
  rs[t] = v0 + v1; rq[t] = v0 * v0 + v1 * v1;
  __syncthreads();
  for (int o = 128; o > 0; o >>= 1) {
    if (t < o) { rs[t] += rs[t + o]; rq[t] += rq[t + o]; }
    __syncthreads();
  }
  float mean = rs[0] * (1.f / 512.f);
  float var  = rq[0] * (1.f / 512.f) - mean * mean;
  float inv  = rsqrtf(var + 1e-5f);
  unsigned short* y = Y + (size_t)row * DIM;
  y[t]       = f2bu((v0 - mean) * inv * ldin(g, t, isbf)       + ldin(b, t, isbf));
  y[t + 256] = f2bu((v1 - mean) * inv * ldin(g, t + 256, isbf) + ldin(b, t + 256, isbf));
}

__global__ void rms512_k(const float* __restrict__ X, const void* __restrict__ g,
                         int goff, unsigned short* __restrict__ Y, const int* __restrict__ flagp) {
  const bool isbf = *flagp != 0;
  int row = blockIdx.x, t = threadIdx.x;
  const float* x = X + (size_t)row * DIM;
  float v0 = x[t], v1 = x[t + 256];
  __shared__ float rq[256];
  rq[t] = v0 * v0 + v1 * v1;
  __syncthreads();
  for (int o = 128; o > 0; o >>= 1) {
    if (t < o) rq[t] += rq[t + o];
    __syncthreads();
  }
  float nrm = sqrtf(rq[0]);
  float sc = 22.62741699796952f / fmaxf(nrm, 1e-12f);
  unsigned short* y = Y + (size_t)row * DIM;
  y[t]       = f2bu(v0 * sc * ldin(g, goff + t, isbf));
  y[t + 256] = f2bu(v1 * sc * ldin(g, goff + t + 256, isbf));
}

// ---------------------------------------------------------------------------
// Slot attention pieces (split kernels — high occupancy)
// ---------------------------------------------------------------------------
__global__ void slot_dots_k(const float* __restrict__ q, const float* __restrict__ k,
                            float* __restrict__ dots) {
  int blk = blockIdx.x;                 // b*200 + h*50 + i
  int i = blk % 50, h = (blk / 50) & 3, b = blk / 200;
  int j = threadIdx.x;
  __shared__ float qs[64];
  if (threadIdx.x < 64) qs[threadIdx.x] = q[((size_t)(b * 50 + i)) * 256 + h * 64 + threadIdx.x];
  __syncthreads();
  const float* kr = k + ((size_t)(b * 256 + j)) * 256 + h * 64;
  float s = 0.f;
#pragma unroll 8
  for (int d = 0; d < 64; ++d) s = fmaf(qs[d], kr[d], s);
  dots[(((size_t)(b * 4 + h) * 50) + i) * 256 + j] = s * 0.125f;
}

// column-wise softmax over slots + 1e-8 (renorm folded into slot_upd_k)
__global__ void colsm_k(float* __restrict__ dots) {
  int idx = blockIdx.x * 256 + threadIdx.x;
  if (idx >= 4096) return;
  int j = idx & 255, bh = idx >> 8;
  float* base = dots + ((size_t)bh * NSL) * 256 + j;
  float v[NSL];
#pragma unroll
  for (int i = 0; i < NSL; ++i) v[i] = base[i * 256];
  float m = -1e30f;
#pragma unroll
  for (int i = 0; i < NSL; ++i) m = fmaxf(m, v[i]);
  float s = 0.f;
#pragma unroll
  for (int i = 0; i < NSL; ++i) { float e = __expf(v[i] - m); v[i] = e; s += e; }
  float inv = 1.f / s;
#pragma unroll
  for (int i = 0; i < NSL; ++i) base[i * 256] = fmaf(v[i], inv, 1e-8f);
}

// upd[i][d] = sum_j a[i][j] v[j][d] / sum_j a[i][j]  (renorm folded)
__global__ void slot_upd_k(const float* __restrict__ attn, const float* __restrict__ v,
                           float* __restrict__ upd) {
  int bi = blockIdx.x;        // b*50+i
  int b = bi / 50, i = bi % 50;
  int t = threadIdx.x, h = t >> 6, lane = t & 63;
  const float* arow = attn + ((size_t)((b * 4 + h) * 50) + i) * 256;
  // wave-level row sum (h uniform within wave)
  float s4 = arow[lane] + arow[lane + 64] + arow[lane + 128] + arow[lane + 192];
#pragma unroll
  for (int o = 1; o < 64; o <<= 1) s4 += __shfl_xor(s4, o);
  float inv = 1.f / s4;
  float s = 0.f;
  for (int j = 0; j < 256; ++j) s = fmaf(arow[j], v[((size_t)(b * 256 + j)) * 256 + t], s);
  upd[(size_t)bi * 256 + t] = s * inv;
}

// fused GRU + LayerNorm(ff): one row per block; writes SLOTS f32 + SLNB bf16
__global__ __launch_bounds__(256) void gruln_k(
    const float* __restrict__ gx, const float* __restrict__ gh,
    float* __restrict__ slots, const void* __restrict__ g, const void* __restrict__ bb,
    unsigned short* __restrict__ Y, const int* __restrict__ flagp) {
  const bool isbf = *flagp != 0;
  int row = blockIdx.x, t = threadIdx.x;
  size_t b3 = (size_t)row * 1536;
  float s01[2];
#pragma unroll
  for (int half = 0; half < 2; ++half) {
    int d = t + half * 256;
    float xr = gx[b3 + d], xz = gx[b3 + 512 + d], xn = gx[b3 + 1024 + d];
    float hr = gh[b3 + d], hz = gh[b3 + 512 + d], hn = gh[b3 + 1024 + d];
    float r = 1.f / (1.f + expf(-(xr + hr)));
    float z = 1.f / (1.f + expf(-(xz + hz)));
    float n = tanhf(xn + r * hn);
    float prev = slots[(size_t)row * DIM + d];
    s01[half] = (1.f - z) * n + z * prev;
    slots[(size_t)row * DIM + d] = s01[half];
  }
  __shared__ float rs[256], rq[256];
  rs[t] = s01[0] + s01[1];
  rq[t] = s01[0] * s01[0] + s01[1] * s01[1];
  __syncthreads();
  for (int o = 128; o > 0; o >>= 1) {
    if (t < o) { rs[t] += rs[t + o]; rq[t] += rq[t + o]; }
    __syncthreads();
  }
  float mean = rs[0] * (1.f / 512.f);
  float var  = rq[0] * (1.f / 512.f) - mean * mean;
  float inv  = rsqrtf(var + 1e-5f);
  unsigned short* y = Y + (size_t)row * DIM;
  y[t]       = f2bu((s01[0] - mean) * inv * ldin(g, t, isbf)       + ldin(bb, t, isbf));
  y[t + 256] = f2bu((s01[1] - mean) * inv * ldin(g, t + 256, isbf) + ldin(bb, t + 256, isbf));
}

// ---------------------------------------------------------------------------
// Transformer pieces
// ---------------------------------------------------------------------------
__global__ void build_x_k(const float* __restrict__ slots, const float* __restrict__ tok,
                          float* __restrict__ x) {
  int i = blockIdx.x * 256 + threadIdx.x;
  if (i >= NB * NT * DIM) return;
  int d = i & 511, n = (i >> 9) % NT, b = i / (NT * DIM);
  x[i] = (n < NSL) ? slots[((size_t)(b * NSL + n)) * DIM + d]
                   : tok[((size_t)(b * HWT + (n - NSL))) * DIM + d];
}

// ---------------------------------------------------------------------------
// Fused attention: per block = 32 q-rows x one (b,h). S = QK^T*0.125 + bias
// (f32 LDS), in-block softmax (8 lanes/row), P bf16 in place, O = P V.
// Token-token bias from 31x31 delta TABLE staged in LDS; slot pairs read BIAS.
// grid (10, 32). LDS ~60 KB.
// ---------------------------------------------------------------------------
__global__ __launch_bounds__(256) void attn_fused_k(
    const unsigned short* __restrict__ Qb, const unsigned short* __restrict__ Kb,
    const unsigned short* __restrict__ Vb, const float* __restrict__ bias,
    const float* __restrict__ tab, unsigned short* __restrict__ Ob)
{
  const int bh = blockIdx.y, b = bh >> 3, h = bh & 7;
  const int i0 = blockIdx.x * 32;
  __shared__ unsigned short Qs[32 * 72];
  __shared__ unsigned short Ks[64 * 72];
  __shared__ float S[32 * 332];
  __shared__ float TabS[961];
  unsigned short* P = (unsigned short*)S;   // bf16 prob, row stride 664 shorts

  const int tid = threadIdx.x;
  const int lane = tid & 63, wave = tid >> 6, quad = lane >> 4, ti = lane & 15;
  const int mi = wave & 1, nh = wave >> 1;

  // ---- stage token-token delta table (h slice) ----
  for (int e = tid; e < 961; e += 256) TabS[e] = tab[e * 8 + h];

  // ---- load Q tile (32 x 64) ----
  {
    int r = tid >> 3, c = (tid & 7) * 8;
    int gi = i0 + r;
    ushort4 u0 = {0,0,0,0}, u1 = {0,0,0,0};
    if (gi < NT) {
      const ushort4* p = (const ushort4*)(Qb + ((size_t)(b * NT + gi)) * DIM + h * 64 + c);
      u0 = p[0]; u1 = p[1];
    }
    *(ushort4*)&Qs[r * 72 + c] = u0;
    *(ushort4*)&Qs[r * 72 + c + 4] = u1;
  }

  // ---- phase 1: scores ----
  for (int kt = 0; kt < 5; ++kt) {
    __syncthreads();
    {
      int kr = tid >> 2, c = (tid & 3) * 16;
      int gj = kt * 64 + kr;
      ushort4 v[4] = {{0,0,0,0},{0,0,0,0},{0,0,0,0},{0,0,0,0}};
      if (gj < NT) {
        const ushort4* p = (const ushort4*)(Kb + ((size_t)(b * NT + gj)) * DIM + h * 64 + c);
#pragma unroll
        for (int i = 0; i < 4; ++i) v[i] = p[i];
      }
#pragma unroll
      for (int i = 0; i < 4; ++i) *(ushort4*)&Ks[kr * 72 + c + i * 4] = v[i];
    }
    __syncthreads();
#pragma unroll
    for (int ntl = 0; ntl < 2; ++ntl) {
      int nt = nh * 2 + ntl;
      float4v acc = {0,0,0,0};
#pragma unroll
      for (int ks = 0; ks < 2; ++ks) {
        short8v a  = *(const short8v*)&Qs[(mi * 16 + ti) * 72 + ks * 32 + quad * 8];
        short8v bb = *(const short8v*)&Ks[(nt * 16 + ti) * 72 + ks * 32 + quad * 8];
        acc = __builtin_amdgcn_mfma_f32_16x16x32_bf16(a, bb, acc, 0, 0, 0);
      }
      int colL = kt * 64 + nt * 16 + ti;
      int row0 = mi * 16 + quad * 4;
#pragma unroll
      for (int r = 0; r < 4; ++r) {
        int row_g = i0 + row0 + r;
        float val;
        if (colL < NT) {
          float bv = 0.f;
          if (row_g < NT) {
            if (row_g >= NSL && colL >= NSL) {
              int ii = row_g - NSL, jj = colL - NSL;
              int di = (ii >> 4) - (jj >> 4) + 15;
              int dj = (ii & 15) - (jj & 15) + 15;
              bv = TabS[di * 31 + dj];
            } else {
              bv = bias[((size_t)bh * NT + row_g) * NT + colL];
            }
          }
          val = acc[r] * 0.125f + bv;
        } else val = -1e30f;
        S[(row0 + r) * 332 + colL] = val;
      }
    }
  }
  __syncthreads();

  // ---- phase 2: softmax (rows in regs), write P bf16 in place ----
  {
    int rl = tid >> 3, sub = tid & 7;
    float sv[40];
#pragma unroll
    for (int k = 0; k < 40; ++k) sv[k] = S[rl * 332 + sub + k * 8];
    float m = -1e30f;
#pragma unroll
    for (int k = 0; k < 40; ++k) m = fmaxf(m, sv[k]);
    m = fmaxf(m, __shfl_xor(m, 1));
    m = fmaxf(m, __shfl_xor(m, 2));
    m = fmaxf(m, __shfl_xor(m, 4));
    float s = 0.f;
#pragma unroll
    for (int k = 0; k < 40; ++k) { float e = __expf(sv[k] - m); sv[k] = e; s += e; }
    s += __shfl_xor(s, 1);
    s += __shfl_xor(s, 2);
    s += __shfl_xor(s, 4);
    float inv = 1.f / s;
    __syncthreads();   // all S reads complete before bf16 overwrite
#pragma unroll
    for (int k = 0; k < 40; ++k) P[rl * 664 + sub + k * 8] = f2bu(sv[k] * inv);
  }

  // ---- phase 3: O = P V ----
  float4v oacc[2] = {{0,0,0,0},{0,0,0,0}};
  for (int vt = 0; vt < 5; ++vt) {
    __syncthreads();
    {
      int key = tid & 63, d0 = (tid >> 6) * 16;
      int gj = vt * 64 + key;
      unsigned short hv[16];
      if (gj < NT) {
        const ushort4* p = (const ushort4*)(Vb + ((size_t)(b * NT + gj)) * DIM + h * 64 + d0);
#pragma unroll
        for (int i = 0; i < 4; ++i) {
          ushort4 u = p[i];
          hv[i*4+0]=u.x; hv[i*4+1]=u.y; hv[i*4+2]=u.z; hv[i*4+3]=u.w;
        }
      } else {
#pragma unroll
        for (int i = 0; i < 16; ++i) hv[i] = 0;
      }
#pragma unroll
      for (int i = 0; i < 16; ++i) Ks[(d0 + i) * 72 + key] = hv[i];
    }
    __syncthreads();
#pragma unroll
    for (int ntl = 0; ntl < 2; ++ntl) {
      int nt = nh * 2 + ntl;
#pragma unroll
      for (int ks = 0; ks < 2; ++ks) {
        short8v a  = *(const short8v*)&P[(mi * 16 + ti) * 664 + vt * 64 + ks * 32 + quad * 8];
        short8v bb = *(const short8v*)&Ks[(nt * 16 + ti) * 72 + ks * 32 + quad * 8];
        oacc[ntl] = __builtin_amdgcn_mfma_f32_16x16x32_bf16(a, bb, oacc[ntl], 0, 0, 0);
      }
    }
  }

  // ---- write O ----
#pragma unroll
  for (int ntl = 0; ntl < 2; ++ntl) {
    int dim = nh * 32 + ntl * 16 + ti;
#pragma unroll
    for (int r = 0; r < 4; ++r) {
      int row_g = i0 + mi * 16 + quad * 4 + r;
      if (row_g < NT)
        Ob[((size_t)(b * NT + row_g)) * DIM + h * 64 + dim] = f2bu(oacc[ntl][r]);
    }
  }
}

// ---------------------------------------------------------------------------
extern "C" void kernel_launch(void* const* d_in, const int* in_sizes, int n_in,
                              void* d_out, int out_size, void* d_ws, size_t ws_size,
                              hipStream_t stream) {
  const void* images        = d_in[0];
  const void* slot_noise    = d_in[1];
  const void* patch_w       = d_in[2];
  const void* patch_b       = d_in[3];
  const void* hpos          = d_in[4];
  const void* wpos          = d_in[5];
  const void* rp_w1         = d_in[6];
  const void* rp_b1         = d_in[7];
  const void* rp_w2         = d_in[8];
  const void* rp_b2         = d_in[9];
  const void* rp_w3         = d_in[10];
  const void* rp_b3         = d_in[11];
  const void* slots_mu      = d_in[12];
  const void* slots_logsig  = d_in[13];
  const void* sa_ln_in_g    = d_in[14];
  const void* sa_ln_in_b    = d_in[15];
  const void* sa_ln_sl_g    = d_in[16];
  const void* sa_ln_sl_b    = d_in[17];
  const void* sa_wq         = d_in[18];
  const void* sa_bq         = d_in[19];
  const void* sa_wk         = d_in[20];
  const void* sa_bk         = d_in[21];
  const void* sa_wv         = d_in[22];
  const void* sa_bv         = d_in[23];
  const void* sa_wo         = d_in[24];
  const void* sa_bo         = d_in[25];
  const void* gru_wih       = d_in[26];
  const void* gru_whh       = d_in[27];
  const void* gru_bih       = d_in[28];
  const void* gru_bhh       = d_in[29];
  const void* sa_ln_ff_g    = d_in[30];
  const void* sa_ln_ff_b    = d_in[31];
  const void* sa_mlp_w1     = d_in[32];
  const void* sa_mlp_b1     = d_in[33];
  const void* sa_mlp_w2     = d_in[34];
  const void* sa_mlp_b2     = d_in[35];
  const void* s2c_w         = d_in[36];
  const void* s2c_b         = d_in[37];
  const void* attn_g        = d_in[38];
  const void* wq            = d_in[39];
  const void* wk            = d_in[40];
  const void* wv            = d_in[41];
  const void* wo            = d_in[42];
  const void* ff_g          = d_in[43];
  const void* ff_w1         = d_in[44];
  const void* ff_b1         = d_in[45];
  const void* ff_w2         = d_in[46];
  const void* ff_b2         = d_in[47];
  const void* final_g       = d_in[48];
  const void* pred_w        = d_in[49];
  const void* pred_b        = d_in[50];

  float* ws = (float*)d_ws;
  int* FLAG = (int*)ws;
  size_t off = 16;
  auto alloc = [&](size_t n) { float* p = ws + off; off += (n + 15) & ~(size_t)15; return p; };
  float* TOK   = alloc((size_t)NB * HWT * DIM);
  unsigned short* INPB = (unsigned short*)alloc((size_t)NB * HWT * DIM / 2);
  float* KB    = alloc((size_t)NB * HWT * 256);
  float* VB    = alloc((size_t)NB * HWT * 256);
  float* SLOTS = alloc((size_t)NB * NSL * DIM);
  unsigned short* SLNB = (unsigned short*)alloc((size_t)NB * NSL * DIM / 2);
  float* QB    = alloc((size_t)NB * NSL * 256);
  float* ATT   = alloc((size_t)NB * 4 * NSL * HWT);
  float* UPD   = alloc((size_t)NB * NSL * 256);
  float* UPDP  = alloc((size_t)NB * NSL * DIM);
  unsigned short* HIDSB = (unsigned short*)alloc((size_t)NB * NSL * DIM / 2);
  float* CRD   = alloc((size_t)NB * NT * 2);
  float* TAB   = alloc((size_t)961 * 8);
  float* BIAS  = alloc((size_t)NB * NH * NT * NT);
  float* X     = alloc((size_t)NB * NT * DIM);
  unsigned short* HBB  = (unsigned short*)alloc((size_t)NB * NT * DIM / 2);
  unsigned short* QHB  = (unsigned short*)alloc((size_t)NB * NT * DIM / 2);
  unsigned short* KHB  = (unsigned short*)alloc((size_t)NB * NT * DIM / 2);
  unsigned short* VHB  = (unsigned short*)alloc((size_t)NB * NT * DIM / 2);
  float* SIM   = alloc((size_t)NB * NH * NT * NT);        // GRU-gate alias space
  unsigned short* OBB  = (unsigned short*)alloc((size_t)NB * NT * DIM / 2);
  unsigned short* FFHB = (unsigned short*)alloc((size_t)NB * NT * FF / 2);
  float* OUTT  = alloc((size_t)NB * NT * DIM);
  // aliases (dead-region reuse)
  unsigned short* XPB = (unsigned short*)OUTT;            // im2col; OUTT otherwise unused
  float* GX = SIM;                                        // GRU gates; dead before transformer
  float* GH = SIM + (size_t)NB * NSL * 1536;
  // transposed-weight arena (bf16 [N,K] per weight)
  const size_t oPatch = 0;
  const size_t oKw    = oPatch + (size_t)512 * 768;
  const size_t oVw    = oKw    + (size_t)256 * 512;
  const size_t oQw    = oVw    + (size_t)256 * 512;
  const size_t oWo    = oQw    + (size_t)256 * 512;
  const size_t oGih   = oWo    + (size_t)512 * 256;
  const size_t oGhh   = oGih   + (size_t)1536 * 512;
  const size_t oMlp1  = oGhh   + (size_t)1536 * 512;
  const size_t oMlp2  = oMlp1  + (size_t)512 * 512;
  const size_t oRp2   = oMlp2  + (size_t)512 * 512;
  const size_t oWq    = oRp2   + (size_t)128 * 128;
  const size_t oWk    = oWq    + (size_t)6 * 512 * 512;
  const size_t oWv    = oWk    + (size_t)6 * 512 * 512;
  const size_t oWol   = oWv    + (size_t)6 * 512 * 512;
  const size_t oFf1   = oWol   + (size_t)6 * 512 * 512;
  const size_t oFf2   = oFf1   + (size_t)6 * 512 * 2048;
  const size_t oPred  = oFf2   + (size_t)6 * 2048 * 512;
  const size_t wtTotal = oPred + (size_t)512 * 512;
  unsigned short* WTS = (unsigned short*)alloc((wtTotal + 1) / 2);
  (void)ws_size; (void)in_sizes; (void)n_in; (void)out_size;

#define GEMMM(A_, ATY_, WOFF_, BIAS_, BOFF_, C_, OTY_, M_, N_, K_, ACT_, ACC_, ZS_, SPEC_, P0_, P1_) \
  gemm_mfma<<<dim3((N_)/64, CDIV((M_),64), (ZS_)), 256, 0, stream>>>( \
      A_, ATY_, WTS, (size_t)(WOFF_), BIAS_, (size_t)(BOFF_), C_, OTY_, M_, N_, K_, ACT_, ACC_, ZS_, \
      SPEC_, P0_, P1_, FLAG)

  const int MROW = NB * NT;   // 1224
  const int MS   = NB * NSL;  // 200

  // ---- dtype detection; merged patchify+slots_init; batched weight transpose ----
  detect_k<<<1, 256, 0, stream>>>(images, FLAG);
  prep_k<<<3472, 256, 0, stream>>>(images, XPB, slots_mu, slots_logsig, slot_noise, SLOTS, FLAG);
  {
    WtArgs a;
    const void* Wp[17] = { patch_w, sa_wk, sa_wv, sa_wq, sa_wo, gru_wih, gru_whh,
                           sa_mlp_w1, sa_mlp_w2, rp_w2, wq, wk, wv, wo, ff_w1, ff_w2, pred_w };
    const size_t Oo[17] = { oPatch, oKw, oVw, oQw, oWo, oGih, oGhh,
                            oMlp1, oMlp2, oRp2, oWq, oWk, oWv, oWol, oFf1, oFf2, oPred };
    const int Kk[17] = {768,512,512,512,256,512,512,512,512,128,512,512,512,512,512,2048,512};
    const int Nn[17] = {512,256,256,256,512,1536,1536,512,512,128,512,512,512,512,2048,512,512};
    const int Ll[17] = {1,1,1,1,1,1,1,1,1,1,6,6,6,6,6,6,1};
    int acc = 0;
    for (int i = 0; i < 17; ++i) {
      a.W[i] = Wp[i]; a.wto[i] = Oo[i]; a.K[i] = Kk[i]; a.N[i] = Nn[i];
      a.base[i] = acc;
      acc += Ll[i] * (Kk[i] >> 7) * (Nn[i] >> 6);
    }
    a.base[17] = acc;
    wtrans_all_k<<<acc, 256, 0, stream>>>(a, WTS, FLAG);
  }

  // ---- patch embed (K-split 3, atomic into zeroed TOK; bias+pos at kbeg==0) ----
  hipMemsetAsync(TOK, 0, (size_t)NB * HWT * DIM * sizeof(float), stream);
  GEMMM(XPB, 1, oPatch, patch_b, 0, TOK, 0, NB*HWT, DIM, 768, 0, 0, 3, 2, hpos, wpos);

  // ---- slot attention: k, v ----
  ln512_k<<<NB*HWT, 256, 0, stream>>>(TOK, sa_ln_in_g, sa_ln_in_b, INPB, FLAG);
  gemm_mfma_duo<<<dim3(4, 16, 2), 256, 0, stream>>>(
      INPB, INPB, 1, WTS, oKw, oVw, sa_bk, sa_bv, KB, VB, 0, NB*HWT, 256, DIM, FLAG);

  for (int it = 0; it < 3; ++it) {
    ln512_k<<<MS, 256, 0, stream>>>(SLOTS, sa_ln_sl_g, sa_ln_sl_b, SLNB, FLAG);
    GEMMM(SLNB, 1, oQw, sa_bq, 0, QB, 0, MS, 256, DIM, 0, 0, 1, 0, nullptr, nullptr);
    slot_dots_k<<<NB*4*NSL, 256, 0, stream>>>(QB, KB, ATT);
    colsm_k<<<16, 256, 0, stream>>>(ATT);
    slot_upd_k<<<MS, 256, 0, stream>>>(ATT, VB, UPD);
    GEMMM(UPD, 0, oWo, sa_bo, 0, UPDP, 0, MS, DIM, 256, 0, 0, 1, 0, nullptr, nullptr);
    gemm_mfma_duo<<<dim3(24, 4, 2), 256, 0, stream>>>(
        UPDP, SLOTS, 0, WTS, oGih, oGhh, gru_bih, gru_bhh, GX, GH, 0, MS, 1536, DIM, FLAG);
    gruln_k<<<MS, 256, 0, stream>>>(GX, GH, SLOTS, sa_ln_ff_g, sa_ln_ff_b, SLNB, FLAG);
    GEMMM(SLNB, 1, oMlp1, sa_mlp_b1, 0, HIDSB, 1, MS, DIM, DIM, 1, 0, 1, 0, nullptr, nullptr);
    GEMMM(HIDSB, 1, oMlp2, sa_mlp_b2, 0, SLOTS, 0, MS, DIM, DIM, 0, 1, 1, 0, nullptr, nullptr);
  }

  // ---- rel-pos bias (fused MLP for slot-involving pairs; token-token via TAB) ----
  coords_table_k<<<1162, 256, 0, stream>>>(SLOTS, s2c_w, s2c_b,
      rp_w1, rp_b1, rp_w2, rp_b2, rp_w3, rp_b3, CRD, TAB, FLAG);
  rp_fused_k<<<CDIV(NPR, 64), 256, 0, stream>>>(
      CRD, rp_w1, rp_b1, WTS, oRp2, rp_b2, rp_w3, rp_b3, BIAS, FLAG);

  // ---- transformer ----
  build_x_k<<<CDIV(NB*NT*DIM, 256), 256, 0, stream>>>(SLOTS, TOK, X);
  for (int l = 0; l < 6; ++l) {
    size_t lw = (size_t)l * 512 * 512;
    rms512_k<<<MROW, 256, 0, stream>>>(X, attn_g, l * DIM, HBB, FLAG);
    gemm_mfma_tri<<<dim3(8, 20, 3), 256, 0, stream>>>(
        HBB, 1, WTS, oWq + lw, oWk + lw, oWv + lw, QHB, KHB, VHB, 1, MROW, DIM, DIM, FLAG);
    attn_fused_k<<<dim3(10, NB*NH), 256, 0, stream>>>(QHB, KHB, VHB, BIAS, TAB, OBB);
    GEMMM(OBB, 1, oWol + lw, (const void*)nullptr, 0, X, 0, MROW, DIM, DIM, 0, 1, 2, 0, nullptr, nullptr);
    rms512_k<<<MROW, 256, 0, stream>>>(X, ff_g, l * DIM, HBB, FLAG);
    GEMMM(HBB, 1, oFf1 + (size_t)l * 512 * 2048, ff_b1, l * FF, FFHB, 1, MROW, FF, DIM, 2, 0, 1, 0, nullptr, nullptr);
    GEMMM(FFHB, 1, oFf2 + (size_t)l * 2048 * 512, ff_b2, l * DIM, X, 0, MROW, DIM, FF, 0, 1, 4, 0, nullptr, nullptr);
  }

  // ---- head: final RMSNorm + GEMM over token rows only (A-remap, M=1024) ----
  rms512_k<<<MROW, 256, 0, stream>>>(X, final_g, 0, HBB, FLAG);
  GEMMM(HBB, 1, oPred, pred_b, 0, d_out, 0, 1024, DIM, DIM, 0, 0, 1, 3, nullptr, nullptr);

#undef GEMMM
}